// Round 19
// baseline (953.957 us; speedup 1.0000x reference)
//
#include <hip/hip_runtime.h>
#include <math.h>

#define BB 2
#define SS 2048
#define DD 512
#define HH 8
#define HDD 64
#define RANKK 128
#define DFFF 1024

typedef short bf16x8 __attribute__((ext_vector_type(8)));
typedef float f32x4 __attribute__((ext_vector_type(4)));

__device__ __forceinline__ short f2b(float f) {
  union { float f; unsigned u; } v; v.f = f;
  unsigned r = v.u + 0x7FFF + ((v.u >> 16) & 1);
  return (short)(r >> 16);
}
__device__ __forceinline__ float b2f(short s) {
  union { unsigned u; float f; } v; v.u = ((unsigned)(unsigned short)s) << 16;
  return v.f;
}

__device__ __forceinline__ void gll16(const void* g, void* l) {
  __builtin_amdgcn_global_load_lds(
      (const __attribute__((address_space(1))) unsigned int*)g,
      (__attribute__((address_space(3))) unsigned int*)l, 16, 0, 0);
}

__device__ __forceinline__ float wsum(float v) {
#pragma unroll
  for (int off = 32; off > 0; off >>= 1) v += __shfl_xor(v, off, 64);
  return v;
}

// ---------------- 4-way weight split fp32 -> hi/lo bf16 ----------------
__global__ void splitw4(const float* __restrict__ w0, const float* __restrict__ w1,
                        const float* __restrict__ w2, const float* __restrict__ w3,
                        short* h0, short* l0_, short* h1, short* l1_,
                        short* h2_, short* l2_, short* h3_, short* l3_) {
  const int z = blockIdx.z;
  const float* in = (z == 0) ? w0 : (z == 1) ? w1 : (z == 2) ? w2 : w3;
  short* hi = (z == 0) ? h0 : (z == 1) ? h1 : (z == 2) ? h2_ : h3_;
  short* lo = (z == 0) ? l0_ : (z == 1) ? l1_ : (z == 2) ? l2_ : l3_;
  int i = (blockIdx.x * 256 + threadIdx.x) * 4;
  if (i >= DD * DD) return;
  float4 v = *(const float4*)(in + i);
  short4 h4, l4;
  h4.x = f2b(v.x); l4.x = f2b(v.x - b2f(h4.x));
  h4.y = f2b(v.y); l4.y = f2b(v.y - b2f(h4.y));
  h4.z = f2b(v.z); l4.z = f2b(v.z - b2f(h4.z));
  h4.w = f2b(v.w); l4.w = f2b(v.w - b2f(h4.w));
  *(short4*)(hi + i) = h4;
  *(short4*)(lo + i) = l4;
}

// ---------------- tril(lat) -> split bf16 hi/lo ----------------
__global__ void splitlat(const float* __restrict__ lat, short* __restrict__ hi,
                         short* __restrict__ lo) {
  int i = (blockIdx.x * 256 + threadIdx.x) * 4;
  int r = i >> 11;
  int c = i & 2047;
  float4 v = *(const float4*)(lat + i);
  if (c + 0 > r) v.x = 0.0f;
  if (c + 1 > r) v.y = 0.0f;
  if (c + 2 > r) v.z = 0.0f;
  if (c + 3 > r) v.w = 0.0f;
  short4 h4, l4;
  h4.x = f2b(v.x); l4.x = f2b(v.x - b2f(h4.x));
  h4.y = f2b(v.y); l4.y = f2b(v.y - b2f(h4.y));
  h4.z = f2b(v.z); l4.z = f2b(v.z - b2f(h4.z));
  h4.w = f2b(v.w); l4.w = f2b(v.w - b2f(h4.w));
  *(short4*)(hi + i) = h4;
  *(short4*)(lo + i) = l4;
}

// ---------------- fp32 -> bf16 single ----------------
__global__ void cvtb(const float* __restrict__ in, short* __restrict__ out, int n) {
  int i = (blockIdx.x * 256 + threadIdx.x) * 4;
  if (i >= n) return;
  float4 v = *(const float4*)(in + i);
  short4 o; o.x = f2b(v.x); o.y = f2b(v.y); o.z = f2b(v.z); o.w = f2b(v.w);
  *(short4*)(out + i) = o;
}

// ---------------- elementwise sum (in-place capable): o = a + b ----------------
__global__ void sum2(const float* __restrict__ a, const float* __restrict__ bq,
                     float* __restrict__ o) {
  int i = (blockIdx.x * 256 + threadIdx.x) * 4;
  float4 va = *(const float4*)(a + i);
  float4 vb = *(const float4*)(bq + i);
  float4 vo = {va.x + vb.x, va.y + vb.y, va.z + vb.z, va.w + vb.w};
  *(float4*)(o + i) = vo;
}

// ---------------- transpose + convert: in f32 [R][C] -> out bf16 [C][R] ----------------
__global__ void transp_cvt(const float* __restrict__ in, short* __restrict__ out,
                           int R, int C) {
  __shared__ float t[32][33];
  int c0 = blockIdx.x * 32, r0 = blockIdx.y * 32;
#pragma unroll
  for (int i = 0; i < 4; i++) {
    int idx = threadIdx.x + i * 256;
    int r = idx >> 5, c = idx & 31;
    t[r][c] = in[(size_t)(r0 + r) * C + c0 + c];
  }
  __syncthreads();
#pragma unroll
  for (int i = 0; i < 4; i++) {
    int idx = threadIdx.x + i * 256;
    int cc = idx >> 5, rr = idx & 31;
    out[(size_t)(c0 + cc) * R + r0 + rr] = f2b(t[rr][cc]);
  }
}

// ---------------- rmsnorm fp32 -> split bf16 ----------------
__global__ void rmsnorm_hl(const float* __restrict__ x, const float* __restrict__ w,
                           short* __restrict__ oh, short* __restrict__ ol, int rows) {
  int wid = blockIdx.x * 4 + (threadIdx.x >> 6);
  int lane = threadIdx.x & 63;
  if (wid >= rows) return;
  const float* xp = x + (size_t)wid * DD + lane * 8;
  float4 a = *(const float4*)xp;
  float4 b = *(const float4*)(xp + 4);
  float ss = a.x*a.x + a.y*a.y + a.z*a.z + a.w*a.w
           + b.x*b.x + b.y*b.y + b.z*b.z + b.w*b.w;
  ss = wsum(ss);
  float r = rsqrtf(ss * (1.0f / DD) + 1e-6f);
  const float* wp = w + lane * 8;
  float4 wa = *(const float4*)wp, wb = *(const float4*)(wp + 4);
  float o8[8] = {a.x*r*wa.x, a.y*r*wa.y, a.z*r*wa.z, a.w*r*wa.w,
                 b.x*r*wb.x, b.y*r*wb.y, b.z*r*wb.z, b.w*r*wb.w};
  short hv[8], lv[8];
#pragma unroll
  for (int i = 0; i < 8; i++) { hv[i] = f2b(o8[i]); lv[i] = f2b(o8[i] - b2f(hv[i])); }
  short* op = oh + (size_t)wid * DD + lane * 8;
  short* lp = ol + (size_t)wid * DD + lane * 8;
  *(short4*)op = make_short4(hv[0], hv[1], hv[2], hv[3]);
  *(short4*)(op + 4) = make_short4(hv[4], hv[5], hv[6], hv[7]);
  *(short4*)lp = make_short4(lv[0], lv[1], lv[2], lv[3]);
  *(short4*)(lp + 4) = make_short4(lv[4], lv[5], lv[6], lv[7]);
}

// ======================= unified bf16 GEMM, gll16 staging =======================
template <bool SPL, int OM, bool ROPE>
__global__ __launch_bounds__(256) void ggemm(const short* __restrict__ Ah_g,
                                             const short* __restrict__ Al_g,
                                             const short* __restrict__ Bh_g,
                                             const short* __restrict__ Bl_g,
                                             const float* __restrict__ ADD,
                                             void* __restrict__ C, void* __restrict__ C2,
                                             int M, int N, int K) {
  __shared__ short Ahs[128 * 32];
  __shared__ short Bhs[128 * 32];
  __shared__ short Als[SPL ? 128 * 32 : 8];
  __shared__ short Bls[SPL ? 128 * 32 : 8];
  const int tid = threadIdx.x, l = tid & 63, w = tid >> 6;
  const int wr = (w >> 1) * 64, wc = (w & 1) * 64;
  const int bm = blockIdx.y * 128, bn = blockIdx.x * 128;
  f32x4 acc[4][4] = {};
  for (int k0 = 0; k0 < K; k0 += 32) {
#pragma unroll
    for (int p = 0; p < 2; p++) {
      int row = p * 64 + (tid >> 2), g = tid & 3;
      int swz = (g ^ ((row >> 1) & 3)) * 8;
      gll16(Ah_g + (size_t)(bm + row) * K + k0 + swz, Ahs + p * 2048 + tid * 8);
      gll16(Bh_g + (size_t)(bn + row) * K + k0 + swz, Bhs + p * 2048 + tid * 8);
      if (SPL) {
        gll16(Al_g + (size_t)(bm + row) * K + k0 + swz, Als + p * 2048 + tid * 8);
        gll16(Bl_g + (size_t)(bn + row) * K + k0 + swz, Bls + p * 2048 + tid * 8);
      }
    }
    __syncthreads();
    bf16x8 ah[4], bh[4], al[4], bl[4];
#pragma unroll
    for (int m = 0; m < 4; m++) {
      int r = wr + m * 16 + (l & 15);
      int go = (((l >> 4) ^ ((r >> 1) & 3)) << 3);
      ah[m] = *(const bf16x8*)(Ahs + r * 32 + go);
      if (SPL) al[m] = *(const bf16x8*)(Als + r * 32 + go);
    }
#pragma unroll
    for (int n = 0; n < 4; n++) {
      int r = wc + n * 16 + (l & 15);
      int go = (((l >> 4) ^ ((r >> 1) & 3)) << 3);
      bh[n] = *(const bf16x8*)(Bhs + r * 32 + go);
      if (SPL) bl[n] = *(const bf16x8*)(Bls + r * 32 + go);
    }
#pragma unroll
    for (int m = 0; m < 4; m++)
#pragma unroll
      for (int n = 0; n < 4; n++) {
        acc[m][n] = __builtin_amdgcn_mfma_f32_16x16x32_bf16(ah[m], bh[n], acc[m][n], 0, 0, 0);
        if (SPL) {
          acc[m][n] = __builtin_amdgcn_mfma_f32_16x16x32_bf16(ah[m], bl[n], acc[m][n], 0, 0, 0);
          acc[m][n] = __builtin_amdgcn_mfma_f32_16x16x32_bf16(al[m], bh[n], acc[m][n], 0, 0, 0);
        }
      }
    __syncthreads();
  }
  const int ll = l & 15, lg4 = (l >> 4) * 4;
  if (ROPE) {
#pragma unroll
    for (int m = 0; m < 4; m++)
#pragma unroll
      for (int n = 0; n < 2; n++) {
        int i_ = n * 16 + ll;
        float inv = exp2f(-(float)i_ * (13.287712379549449f / 32.0f));
#pragma unroll
        for (int j = 0; j < 4; j++) {
          int gm = bm + wr + m * 16 + lg4 + j;
          int s = gm & (SS - 1);
          float ang = (float)s * inv;
          float sn, cs;
          sincosf(ang, &sn, &cs);
          float v1 = acc[m][n][j], v2 = acc[m][n + 2][j];
          acc[m][n][j]     = v1 * cs - v2 * sn;
          acc[m][n + 2][j] = v2 * cs + v1 * sn;
        }
      }
  }
#pragma unroll
  for (int m = 0; m < 4; m++)
#pragma unroll
    for (int n = 0; n < 4; n++) {
      int gn = bn + wc + n * 16 + ll;
#pragma unroll
      for (int j = 0; j < 4; j++) {
        int gm = bm + wr + m * 16 + lg4 + j;
        if (gm >= M || gn >= N) continue;
        float v = acc[m][n][j];
        if (OM == 0) {
          ((float*)C)[(size_t)gm * N + gn] = v;
        } else if (OM == 1) {
          ((short*)C)[(size_t)gm * N + gn] = f2b(v);
        } else if (OM == 6) {
          size_t off = (size_t)gm * N + gn;
          ((float*)C)[off] = v + ADD[off];
        } else {
          short hi = f2b(v);
          short lo = f2b(v - b2f(hi));
          int b = gm >> 11, s = gm & (SS - 1);
          int hh2 = gn >> 6, d = gn & 63;
          size_t off;
          if (OM == 2)      off = (((size_t)(b * HH + hh2)) * SS + s) * 64 + d;
          else if (OM == 3) off = (((size_t)(b * HH + hh2)) * 64 + d) * SS + s;
          else              off = ((size_t)(b * DD) + gn) * SS + s;
          ((short*)C)[off] = hi;
          ((short*)C2)[off] = lo;
        }
      }
    }
}

// ======================= fused QKV GEMM: z selects weight/output =======================
__global__ __launch_bounds__(256) void qkv_g(const short* __restrict__ Ah_g,
                                             const short* __restrict__ Al_g,
                                             const short* __restrict__ wh0, const short* __restrict__ wl0,
                                             const short* __restrict__ wh1, const short* __restrict__ wl1,
                                             const short* __restrict__ wh2, const short* __restrict__ wl2,
                                             short* __restrict__ c0h, short* __restrict__ c0l,
                                             short* __restrict__ c1h, short* __restrict__ c1l,
                                             short* __restrict__ c2h, short* __restrict__ c2l) {
  const int z = blockIdx.z;
  const short* Bh_g = (z == 0) ? wh0 : (z == 1) ? wh1 : wh2;
  const short* Bl_g = (z == 0) ? wl0 : (z == 1) ? wl1 : wl2;
  short* Ch = (z == 0) ? c0h : (z == 1) ? c1h : c2h;
  short* Cl = (z == 0) ? c0l : (z == 1) ? c1l : c2l;
  const int K = DD;
  __shared__ short Ahs[128 * 32];
  __shared__ short Bhs[128 * 32];
  __shared__ short Als[128 * 32];
  __shared__ short Bls[128 * 32];
  const int tid = threadIdx.x, l = tid & 63, w = tid >> 6;
  const int wr = (w >> 1) * 64, wc = (w & 1) * 64;
  const int bm = blockIdx.y * 128, bn = blockIdx.x * 128;
  f32x4 acc[4][4] = {};
  for (int k0 = 0; k0 < K; k0 += 32) {
#pragma unroll
    for (int p = 0; p < 2; p++) {
      int row = p * 64 + (tid >> 2), g = tid & 3;
      int swz = (g ^ ((row >> 1) & 3)) * 8;
      gll16(Ah_g + (size_t)(bm + row) * K + k0 + swz, Ahs + p * 2048 + tid * 8);
      gll16(Bh_g + (size_t)(bn + row) * K + k0 + swz, Bhs + p * 2048 + tid * 8);
      gll16(Al_g + (size_t)(bm + row) * K + k0 + swz, Als + p * 2048 + tid * 8);
      gll16(Bl_g + (size_t)(bn + row) * K + k0 + swz, Bls + p * 2048 + tid * 8);
    }
    __syncthreads();
    bf16x8 ah[4], bh[4], al[4], bl[4];
#pragma unroll
    for (int m = 0; m < 4; m++) {
      int r = wr + m * 16 + (l & 15);
      int go = (((l >> 4) ^ ((r >> 1) & 3)) << 3);
      ah[m] = *(const bf16x8*)(Ahs + r * 32 + go);
      al[m] = *(const bf16x8*)(Als + r * 32 + go);
    }
#pragma unroll
    for (int n = 0; n < 4; n++) {
      int r = wc + n * 16 + (l & 15);
      int go = (((l >> 4) ^ ((r >> 1) & 3)) << 3);
      bh[n] = *(const bf16x8*)(Bhs + r * 32 + go);
      bl[n] = *(const bf16x8*)(Bls + r * 32 + go);
    }
#pragma unroll
    for (int m = 0; m < 4; m++)
#pragma unroll
      for (int n = 0; n < 4; n++) {
        acc[m][n] = __builtin_amdgcn_mfma_f32_16x16x32_bf16(ah[m], bh[n], acc[m][n], 0, 0, 0);
        acc[m][n] = __builtin_amdgcn_mfma_f32_16x16x32_bf16(ah[m], bl[n], acc[m][n], 0, 0, 0);
        acc[m][n] = __builtin_amdgcn_mfma_f32_16x16x32_bf16(al[m], bh[n], acc[m][n], 0, 0, 0);
      }
    __syncthreads();
  }
  const int ll = l & 15, lg4 = (l >> 4) * 4;
  if (z < 2) {  // RoPE on q, k
#pragma unroll
    for (int m = 0; m < 4; m++)
#pragma unroll
      for (int n = 0; n < 2; n++) {
        int i_ = n * 16 + ll;
        float inv = exp2f(-(float)i_ * (13.287712379549449f / 32.0f));
#pragma unroll
        for (int j = 0; j < 4; j++) {
          int gm = bm + wr + m * 16 + lg4 + j;
          int s = gm & (SS - 1);
          float ang = (float)s * inv;
          float sn, cs;
          sincosf(ang, &sn, &cs);
          float v1 = acc[m][n][j], v2 = acc[m][n + 2][j];
          acc[m][n][j]     = v1 * cs - v2 * sn;
          acc[m][n + 2][j] = v2 * cs + v1 * sn;
        }
      }
  }
#pragma unroll
  for (int m = 0; m < 4; m++)
#pragma unroll
    for (int n = 0; n < 4; n++) {
      int gn = bn + wc + n * 16 + ll;
#pragma unroll
      for (int j = 0; j < 4; j++) {
        int gm = bm + wr + m * 16 + lg4 + j;
        float v = acc[m][n][j];
        short hi = f2b(v);
        short lo = f2b(v - b2f(hi));
        int b = gm >> 11, s = gm & (SS - 1);
        int hh2 = gn >> 6, d = gn & 63;
        size_t off = (z < 2) ? ((((size_t)(b * HH + hh2)) * SS + s) * 64 + d)
                             : ((((size_t)(b * HH + hh2)) * 64 + d) * SS + s);
        Ch[off] = hi;
        Cl[off] = lo;
      }
    }
}

// ======================= lateral GEMM: pre-split A, split-K=2, rotated output =======================
__global__ __launch_bounds__(256) void lat_g(const short* __restrict__ lath,
                                             const short* __restrict__ latl,
                                             const short* __restrict__ bTh,
                                             const short* __restrict__ bTl,
                                             float* __restrict__ P0,
                                             float* __restrict__ P1) {
  const int zb = blockIdx.z >> 1;
  const int half = blockIdx.z & 1;
  bTh += (size_t)zb * DD * SS;
  bTl += (size_t)zb * DD * SS;
  float* Cc = (half == 0 ? P0 : P1) + (size_t)zb * DD * SS;
  __shared__ short Ah[128 * 32];
  __shared__ short Al[128 * 32];
  __shared__ short Bh[128 * 32];
  __shared__ short Bl[128 * 32];
  const int tid = threadIdx.x, l = tid & 63, w = tid >> 6;
  const int wr = (w >> 1) * 64, wc = (w & 1) * 64;
  const int bm = blockIdx.y * 128, bn = blockIdx.x * 128;
  const int T = blockIdx.y + 1;
  const int h0 = (T + 1) >> 1;
  const int kbeg = (half == 0) ? 0 : h0 * 128;
  const int kend = (half == 0) ? h0 * 128 : T * 128;
  f32x4 acc[4][4] = {};
  const int ll = l & 15, lg4 = (l >> 4) * 4;
  for (int k0 = kbeg; k0 < kend; k0 += 32) {
#pragma unroll
    for (int p = 0; p < 2; p++) {
      int row = p * 64 + (tid >> 2), g = tid & 3;
      int swz = (g ^ ((row >> 1) & 3)) * 8;
      gll16(bTh + (size_t)(bn + row) * SS + k0 + swz, Bh + p * 2048 + tid * 8);
      gll16(bTl + (size_t)(bn + row) * SS + k0 + swz, Bl + p * 2048 + tid * 8);
      gll16(lath + (size_t)(bm + row) * SS + k0 + swz, Ah + p * 2048 + tid * 8);
      gll16(latl + (size_t)(bm + row) * SS + k0 + swz, Al + p * 2048 + tid * 8);
    }
    __syncthreads();
    bf16x8 ah[4], bh[4], al[4], bl[4];
#pragma unroll
    for (int m = 0; m < 4; m++) {
      int r = wr + m * 16 + (l & 15);
      int go = (((l >> 4) ^ ((r >> 1) & 3)) << 3);
      ah[m] = *(const bf16x8*)(Ah + r * 32 + go);
      al[m] = *(const bf16x8*)(Al + r * 32 + go);
    }
#pragma unroll
    for (int n = 0; n < 4; n++) {
      int r = wc + n * 16 + (l & 15);
      int go = (((l >> 4) ^ ((r >> 1) & 3)) << 3);
      bh[n] = *(const bf16x8*)(Bh + r * 32 + go);
      bl[n] = *(const bf16x8*)(Bl + r * 32 + go);
    }
#pragma unroll
    for (int m = 0; m < 4; m++)
#pragma unroll
      for (int n = 0; n < 4; n++) {
        acc[m][n] = __builtin_amdgcn_mfma_f32_16x16x32_bf16(ah[m], bh[n], acc[m][n], 0, 0, 0);
        acc[m][n] = __builtin_amdgcn_mfma_f32_16x16x32_bf16(ah[m], bl[n], acc[m][n], 0, 0, 0);
        acc[m][n] = __builtin_amdgcn_mfma_f32_16x16x32_bf16(al[m], bh[n], acc[m][n], 0, 0, 0);
      }
    __syncthreads();
  }
#pragma unroll
  for (int m = 0; m < 4; m++)
#pragma unroll
    for (int n = 0; n < 4; n++) {
      int gn = bn + wc + n * 16 + ll;
#pragma unroll
      for (int j = 0; j < 4; j++) {
        int gm = bm + wr + m * 16 + lg4 + j;
        size_t off = ((size_t)((gm >> 5) * 512 + gn)) * 32 + ((gm + gn) & 31);
        Cc[off] = acc[m][n][j];
      }
    }
}

// ======================= flash attention (P hi-only PV) =======================
__global__ __launch_bounds__(256) void attn_g(const short* __restrict__ qh,
                                              const short* __restrict__ ql,
                                              const short* __restrict__ kh,
                                              const short* __restrict__ kl,
                                              const short* __restrict__ vh,
                                              const short* __restrict__ vl,
                                              short* __restrict__ aho,
                                              short* __restrict__ alo) {
  const int h = blockIdx.y, b = blockIdx.z;
  const int qt = (b == 0) ? (int)blockIdx.x : 31 - (int)blockIdx.x;
  const int q0 = qt * 64;
  const int tid = threadIdx.x, w = tid >> 6, l = tid & 63;
  const int lg = l >> 4, ll = l & 15;
  __shared__ short Kh[64 * 64], Kl[64 * 64];
  __shared__ short Vh[64 * 64], Vl[64 * 64];
  __shared__ short Ph[64 * 64];
  const size_t bh = (size_t)(b * HH + h);

  const int qr = q0 + w * 16 + ll;
  const short* qbh = qh + (bh * SS + qr) * 64;
  const short* qbl = ql + (bh * SS + qr) * 64;
  bf16x8 qfh[2], qfl[2];
#pragma unroll
  for (int ks = 0; ks < 2; ks++) {
    qfh[ks] = *(const bf16x8*)(qbh + (ks * 4 + lg) * 8);
    qfl[ks] = *(const bf16x8*)(qbl + (ks * 4 + lg) * 8);
  }

  f32x4 o[4] = {};
  float mrow[4] = {-1e30f, -1e30f, -1e30f, -1e30f};
  float lsum[4] = {};
  const int qrow0 = q0 + w * 16 + lg * 4;
  const int ntiles = qt + 1;

  for (int kt = 0; kt < ntiles; kt++) {
#pragma unroll
    for (int p = 0; p < 2; p++) {
      int row = p * 32 + (tid >> 3), g = tid & 7;
      int sw = ((g ^ (row & 7)) << 3);
      size_t krow = (bh * SS + kt * 64 + row) * 64;
      size_t vrow = (bh * 64 + row) * SS + kt * 64;
      gll16(kh + krow + sw, Kh + p * 2048 + tid * 8);
      gll16(kl + krow + sw, Kl + p * 2048 + tid * 8);
      gll16(vh + vrow + sw, Vh + p * 2048 + tid * 8);
      gll16(vl + vrow + sw, Vl + p * 2048 + tid * 8);
    }
    __syncthreads();

    f32x4 sv[4] = {};
#pragma unroll
    for (int nf = 0; nf < 4; nf++) {
      int r = nf * 16 + ll;
#pragma unroll
      for (int ks = 0; ks < 2; ks++) {
        int g = (ks * 4 + lg) ^ (r & 7);
        bf16x8 khf = *(const bf16x8*)(Kh + r * 64 + g * 8);
        bf16x8 klf = *(const bf16x8*)(Kl + r * 64 + g * 8);
        sv[nf] = __builtin_amdgcn_mfma_f32_16x16x32_bf16(qfh[ks], khf, sv[nf], 0, 0, 0);
        sv[nf] = __builtin_amdgcn_mfma_f32_16x16x32_bf16(qfh[ks], klf, sv[nf], 0, 0, 0);
        sv[nf] = __builtin_amdgcn_mfma_f32_16x16x32_bf16(qfl[ks], khf, sv[nf], 0, 0, 0);
      }
    }
#pragma unroll
    for (int nf = 0; nf < 4; nf++) {
      int kpos = kt * 64 + nf * 16 + ll;
#pragma unroll
      for (int j = 0; j < 4; j++) {
        float v = sv[nf][j] * 0.125f;
        sv[nf][j] = (kpos > qrow0 + j) ? -1e30f : v;
      }
    }
    float cf[4];
#pragma unroll
    for (int j = 0; j < 4; j++) {
      float r = fmaxf(fmaxf(sv[0][j], sv[1][j]), fmaxf(sv[2][j], sv[3][j]));
      r = fmaxf(r, __shfl_xor(r, 1)); r = fmaxf(r, __shfl_xor(r, 2));
      r = fmaxf(r, __shfl_xor(r, 4)); r = fmaxf(r, __shfl_xor(r, 8));
      float mn = fmaxf(mrow[j], r);
      cf[j] = __expf(mrow[j] - mn);
      mrow[j] = mn;
    }
    float ps[4] = {};
#pragma unroll
    for (int nf = 0; nf < 4; nf++)
#pragma unroll
      for (int j = 0; j < 4; j++) {
        float p = __expf(sv[nf][j] - mrow[j]);
        sv[nf][j] = p;
        ps[j] += p;
      }
#pragma unroll
    for (int j = 0; j < 4; j++) {
      float r = ps[j];
      r += __shfl_xor(r, 1); r += __shfl_xor(r, 2);
      r += __shfl_xor(r, 4); r += __shfl_xor(r, 8);
      lsum[j] = lsum[j] * cf[j] + r;
    }
#pragma unroll
    for (int nf = 0; nf < 4; nf++)
#pragma unroll
      for (int j = 0; j < 4; j++) o[nf][j] *= cf[j];
    // write P (hi only)
#pragma unroll
    for (int nf = 0; nf < 4; nf++)
#pragma unroll
      for (int j = 0; j < 4; j++) {
        int rowP = w * 16 + lg * 4 + j;
        int col = nf * 16 + ll;
        int off = rowP * 64 + (((col >> 3) ^ (rowP & 7)) << 3) + (col & 7);
        Ph[off] = f2b(sv[nf][j]);
      }
    __syncthreads();
    bf16x8 pfh[2];
    {
      int rowA = w * 16 + ll;
#pragma unroll
      for (int ks = 0; ks < 2; ks++) {
        int g = (ks * 4 + lg) ^ (rowA & 7);
        pfh[ks] = *(const bf16x8*)(Ph + rowA * 64 + g * 8);
      }
    }
#pragma unroll
    for (int nf = 0; nf < 4; nf++) {
      int r = nf * 16 + ll;
#pragma unroll
      for (int ks = 0; ks < 2; ks++) {
        int g = (ks * 4 + lg) ^ (r & 7);
        bf16x8 vhf = *(const bf16x8*)(Vh + r * 64 + g * 8);
        bf16x8 vlf = *(const bf16x8*)(Vl + r * 64 + g * 8);
        o[nf] = __builtin_amdgcn_mfma_f32_16x16x32_bf16(pfh[ks], vhf, o[nf], 0, 0, 0);
        o[nf] = __builtin_amdgcn_mfma_f32_16x16x32_bf16(pfh[ks], vlf, o[nf], 0, 0, 0);
      }
    }
    __syncthreads();
  }
  float inv[4];
#pragma unroll
  for (int j = 0; j < 4; j++) inv[j] = 1.0f / lsum[j];
#pragma unroll
  for (int nf = 0; nf < 4; nf++)
#pragma unroll
    for (int j = 0; j < 4; j++) {
      float v = o[nf][j] * inv[j];
      short hi = f2b(v);
      size_t off = ((size_t)(b * SS + qrow0 + j)) * DD + h * HDD + nf * 16 + ll;
      aho[off] = hi;
      alo[off] = f2b(v - b2f(hi));
    }
}

// ======================= ALIF scan: 4 chains/thread (ILP hides dependent latency) =======================
// 1024 chains = 4 blocks x 64 threads x 4 chains. Thread t, block bk runs
// (b,d) for b in {0,1}, d in {bk*64+t, bk*64+256+t}. Per-chain math identical
// to alif8; the 4 independent chains interleave in program order so the
// ~129cy/step dependent chain of each hides under the others' instructions.
#define ACH 32
__global__ __launch_bounds__(64) void tsa_alif9(const float* __restrict__ mixedS,
                                                const float* __restrict__ bt,
                                                const float* __restrict__ asw,
                                                float* __restrict__ spikesS) {
  __shared__ float lds[2][4][ACH * 64];  // 64 KB
  const int t = threadIdx.x;
  const int dblk = blockIdx.x * 64;
  const int dA = dblk + t, dB = dblk + 256 + t;
  const int d0A = dblk, d0B = dblk + 256;
  const float C = 36.06737602222409f;  // 25 * log2(e)
  const float btA = bt[dA], asA = asw[dA];
  const float btB = bt[dB], asB = asw[dB];
  const float bt36A = btA * C, as36A = asA * C, bt99A = 0.99f * btA, as99A = 0.99f * asA;
  const float bt36B = btB * C, as36B = asB * C, bt99B = 0.99f * btB, as99B = 0.99f * asB;
  const size_t bs = (size_t)DD * SS;
  // tile sources: 0:(b0,d0A) 1:(b0,d0B) 2:(b1,d0A) 3:(b1,d0B)
  const float* src[4] = {mixedS + (size_t)d0A * 32, mixedS + (size_t)d0B * 32,
                         mixedS + bs + (size_t)d0A * 32, mixedS + bs + (size_t)d0B * 32};
  float* dst[4] = {spikesS + (size_t)d0A * 32, spikesS + (size_t)d0B * 32,
                   spikesS + bs + (size_t)d0A * 32, spikesS + bs + (size_t)d0B * 32};
  // prologue: chunk 0 into buffer 0
#pragma unroll
  for (int tl = 0; tl < 4; tl++)
#pragma unroll
    for (int i = 0; i < 8; i++)
      gll16(src[tl] + i * 256 + t * 4, &lds[0][tl][i * 256 + t * 4]);

  float vR0 = 0.f, vR1 = 0.f, vR2 = 0.f, vR3 = 0.f;
  float ad0 = 0.f, ad1 = 0.f, ad2 = 0.f, ad3 = 0.f;

  for (int c = 0; c < SS / ACH; c++) {
    const int cur = c & 1;
    __syncthreads();  // chunk c resident in lds[cur]
    if (c + 1 < SS / ACH) {
      size_t coff = (size_t)(c + 1) * 512 * 32;
#pragma unroll
      for (int tl = 0; tl < 4; tl++)
#pragma unroll
        for (int i = 0; i < 8; i++)
          gll16(src[tl] + coff + i * 256 + t * 4, &lds[cur ^ 1][tl][i * 256 + t * 4]);
    }
#pragma unroll
    for (int j = 0; j < ACH; j++) {
      const int sl = t * 32 + ((j + t) & 31);
      float mj0 = lds[cur][0][sl];
      float mj1 = lds[cur][1][sl];
      float mj2 = lds[cur][2][sl];
      float mj3 = lds[cur][3][sl];
      if (j == 0) { vR0 += mj0; vR1 += mj1; vR2 += mj2; vR3 += mj3; }
      float mn0 = 0.f, mn1 = 0.f, mn2 = 0.f, mn3 = 0.f;
      if (j + 1 < ACH) {
        const int sln = t * 32 + ((j + 1 + t) & 31);
        mn0 = lds[cur][0][sln]; mn1 = lds[cur][1][sln];
        mn2 = lds[cur][2][sln]; mn3 = lds[cur][3][sln];
      }
      // chain 0: (b0, dA)
      {
        float thC = fmaf(ad0, as36A, bt36A);
        float th99 = fmaf(ad0, as99A, bt99A);
        float e = exp2f(fmaf(vR0, -C, thC));
        float s = __builtin_amdgcn_rcpf(1.0f + e);
        lds[cur][0][sl] = s;
        float pre = (j + 1 < ACH) ? fmaf(0.99f, vR0, mn0) : (0.99f * vR0);
        vR0 = fmaf(-th99, s, pre);
        ad0 = fmaf(0.95f, ad0, s);
      }
      // chain 1: (b0, dB)
      {
        float thC = fmaf(ad1, as36B, bt36B);
        float th99 = fmaf(ad1, as99B, bt99B);
        float e = exp2f(fmaf(vR1, -C, thC));
        float s = __builtin_amdgcn_rcpf(1.0f + e);
        lds[cur][1][sl] = s;
        float pre = (j + 1 < ACH) ? fmaf(0.99f, vR1, mn1) : (0.99f * vR1);
        vR1 = fmaf(-th99, s, pre);
        ad1 = fmaf(0.95f, ad1, s);
      }
      // chain 2: (b1, dA)
      {
        float thC = fmaf(ad2, as36A, bt36A);
        float th99 = fmaf(ad2, as99A, bt99A);
        float e = exp2f(fmaf(vR2, -C, thC));
        float s = __builtin_amdgcn_rcpf(1.0f + e);
        lds[cur][2][sl] = s;
        float pre = (j + 1 < ACH) ? fmaf(0.99f, vR2, mn2) : (0.99f * vR2);
        vR2 = fmaf(-th99, s, pre);
        ad2 = fmaf(0.95f, ad2, s);
      }
      // chain 3: (b1, dB)
      {
        float thC = fmaf(ad3, as36B, bt36B);
        float th99 = fmaf(ad3, as99B, bt99B);
        float e = exp2f(fmaf(vR3, -C, thC));
        float s = __builtin_amdgcn_rcpf(1.0f + e);
        lds[cur][3][sl] = s;
        float pre = (j + 1 < ACH) ? fmaf(0.99f, vR3, mn3) : (0.99f * vR3);
        vR3 = fmaf(-th99, s, pre);
        ad3 = fmaf(0.95f, ad3, s);
      }
    }
    __syncthreads();  // spikes resident in lds[cur]
    size_t coff = (size_t)c * 512 * 32;
#pragma unroll
    for (int tl = 0; tl < 4; tl++)
#pragma unroll
      for (int i = 0; i < 8; i++) {
        float4 v4 = *(const float4*)&lds[cur][tl][i * 256 + t * 4];
        *(float4*)(dst[tl] + coff + i * 256 + t * 4) = v4;
      }
  }
}

// ======================= h2 = x + mixedS^T + spikes^T (rotated layouts) =======================
__global__ __launch_bounds__(256) void fuse_h2(const float* __restrict__ x,
                                               const float* __restrict__ mixedS,
                                               const float* __restrict__ spikesS,
                                               float* __restrict__ h2) {
  const int s0 = blockIdx.x * 64, d0 = blockIdx.y * 64, b = blockIdx.z;
  __shared__ float t[64][65];
  const int dl = threadIdx.x >> 2;
  const int grp = threadIdx.x & 3;
  const size_t bbase = (size_t)b * DD * SS;
#pragma unroll
  for (int i = 0; i < 16; i++) {
    int sl = grp * 16 + i;
    int sg = s0 + sl;
    size_t off = bbase + ((size_t)((sg >> 5) * 512 + d0 + dl)) * 32 + ((sg + dl) & 31);
    t[dl][sl] = mixedS[off] + spikesS[off];
  }
  __syncthreads();
#pragma unroll
  for (int k = 0; k < 4; k++) {
    int sl = threadIdx.x >> 2;
    int dl2 = (threadIdx.x & 3) * 16 + k * 4;
    size_t off = ((size_t)(b * SS + s0 + sl)) * DD + d0 + dl2;
    float4 xv = *(const float4*)(x + off);
    float4 o;
    o.x = xv.x + t[dl2 + 0][sl];
    o.y = xv.y + t[dl2 + 1][sl];
    o.z = xv.z + t[dl2 + 2][sl];
    o.w = xv.w + t[dl2 + 3][sl];
    *(float4*)(h2 + off) = o;
  }
}

// ======================= tree kernels =======================
__global__ void tree_reduce_b(const float* __restrict__ sin_, const float* __restrict__ tn1,
                              short* __restrict__ nb, int Sn) {
  int wid = blockIdx.x * 4 + (threadIdx.x >> 6);
  int lane = threadIdx.x & 63;
  int rows = BB * Sn;
  if (wid >= rows) return;
  int b = wid / Sn, j = wid - b * Sn;
  const float* r0 = sin_ + ((size_t)(b * 2 * Sn + 2 * j)) * DD + lane * 8;
  const float* r1 = r0 + DD;
  float4 a0 = *(const float4*)r0, a1 = *(const float4*)(r0 + 4);
  float4 b0 = *(const float4*)r1, b1 = *(const float4*)(r1 + 4);
  float ra[8] = {a0.x + b0.x, a0.y + b0.y, a0.z + b0.z, a0.w + b0.w,
                 a1.x + b1.x, a1.y + b1.y, a1.z + b1.z, a1.w + b1.w};
  float ss = 0.0f;
#pragma unroll
  for (int i = 0; i < 8; i++) ss += ra[i] * ra[i];
  ss = wsum(ss);
  float rms = rsqrtf(ss * (1.0f / DD) + 1e-6f);
  const float* wp = tn1 + lane * 8;
  float4 wa = *(const float4*)wp, wb = *(const float4*)(wp + 4);
  float wv8[8] = {wa.x, wa.y, wa.z, wa.w, wb.x, wb.y, wb.z, wb.w};
  short* np = nb + (size_t)wid * DD + lane * 8;
  short4 n0, n1;
  n0.x = f2b(ra[0]*rms*wv8[0]); n0.y = f2b(ra[1]*rms*wv8[1]);
  n0.z = f2b(ra[2]*rms*wv8[2]); n0.w = f2b(ra[3]*rms*wv8[3]);
  n1.x = f2b(ra[4]*rms*wv8[4]); n1.y = f2b(ra[5]*rms*wv8[5]);
  n1.z = f2b(ra[6]*rms*wv8[6]); n1.w = f2b(ra[7]*rms*wv8[7]);
  *(short4*)np = n0;
  *(short4*)(np + 4) = n1;
}

__global__ void tree_combine_b(const float* __restrict__ g, const short* __restrict__ nb,
                               const float* __restrict__ sin_, const float* __restrict__ tn2,
                               float* __restrict__ sout, int Sn) {
  int wid = blockIdx.x * 4 + (threadIdx.x >> 6);
  int lane = threadIdx.x & 63;
  int rows = BB * Sn;
  if (wid >= rows) return;
  int b = wid / Sn, j = wid - b * Sn;
  const float* r0 = sin_ + ((size_t)(b * 2 * Sn + 2 * j)) * DD + lane * 8;
  const float* r1 = r0 + DD;
  float4 a0 = *(const float4*)r0, a1 = *(const float4*)(r0 + 4);
  float4 b0 = *(const float4*)r1, b1 = *(const float4*)(r1 + 4);
  float res[8] = {0.5f*(a0.x + b0.x), 0.5f*(a0.y + b0.y), 0.5f*(a0.z + b0.z), 0.5f*(a0.w + b0.w),
                  0.5f*(a1.x + b1.x), 0.5f*(a1.y + b1.y), 0.5f*(a1.z + b1.z), 0.5f*(a1.w + b1.w)};
  size_t base = (size_t)wid * DD + lane * 8;
  float t[8];
  float ss = 0.0f;
#pragma unroll
  for (int i = 0; i < 8; i++) {
    float gg = 1.0f / (1.0f + expf(-g[base + i]));
    float tv = gg * b2f(nb[base + i]) + (1.0f - gg) * res[i];
    t[i] = tv;
    ss += tv * tv;
  }
  ss = wsum(ss);
  float rms = rsqrtf(ss * (1.0f / DD) + 1e-6f);
#pragma unroll
  for (int i = 0; i < 8; i++) sout[base + i] = t[i] * rms * tn2[lane * 8 + i];
}

// h3 = h2 + root -> out fp32; hn = rmsnorm(h3) -> bf16
__global__ void h3hn_b(const float* __restrict__ h2, const float* __restrict__ root,
                       const float* __restrict__ fw, float* __restrict__ h3,
                       short* __restrict__ hn) {
  int wid = blockIdx.x * 4 + (threadIdx.x >> 6);
  int lane = threadIdx.x & 63;
  int b = wid >> 11;
  size_t base = (size_t)wid * DD + lane * 8;
  const float* rp = root + (size_t)b * DD + lane * 8;
  float t[8];
  float ss = 0.0f;
#pragma unroll
  for (int i = 0; i < 8; i++) {
    float tv = h2[base + i] + rp[i];
    t[i] = tv;
    ss += tv * tv;
    h3[base + i] = tv;
  }
  ss = wsum(ss);
  float rms = rsqrtf(ss * (1.0f / DD) + 1e-6f);
#pragma unroll
  for (int i = 0; i < 8; i++) hn[base + i] = f2b(t[i] * rms * fw[lane * 8 + i]);
}

// ======================= upgate =======================
__global__ __launch_bounds__(256) void upgate_g(const short* __restrict__ A,
                                                const short* __restrict__ Bv,
                                                short* __restrict__ ffa) {
  __shared__ short Ahs[128 * 32];
  __shared__ short B1s[128 * 32];
  __shared__ short B2s[128 * 32];
  const int tid = threadIdx.x, l = tid & 63, w = tid >> 6;
  const int wr = (w >> 1) * 64, wc = (w & 1) * 64;
  const int bm = blockIdx.y * 128, bn = blockIdx.x * 128;
  f32x4 acc1[4][4] = {}, acc2[4][4] = {};
  for (int k0 = 0; k0 < RANKK; k0 += 32) {
#pragma unroll
    for (int p = 0; p < 2; p++) {
      int row = p * 64 + (tid >> 2), g = tid & 3;
      int swz = (g ^ ((row >> 1) & 3)) * 8;
      gll16(A + (size_t)(bm + row) * RANKK + k0 + swz, Ahs + p * 2048 + tid * 8);
      gll16(Bv + (size_t)(bn + row) * RANKK + k0 + swz, B1s + p * 2048 + tid * 8);
      gll16(Bv + (size_t)(DFFF + bn + row) * RANKK + k0 + swz, B2s + p * 2048 + tid * 8);
    }
    __syncthreads();
    bf16x8 ah[4], b1[4], b2[4];
#pragma unroll
    for (int m = 0; m < 4; m++) {
      int r = wr + m * 16 + (l & 15);
      int go = (((l >> 4) ^ ((r >> 1) & 3)) << 3);
      ah[m] = *(const bf16x8*)(Ahs + r * 32 + go);
    }
#pragma unroll
    for (int n = 0; n < 4; n++) {
      int r = wc + n * 16 + (l & 15);
      int go = (((l >> 4) ^ ((r >> 1) & 3)) << 3);
      b1[n] = *(const bf16x8*)(B1s + r * 32 + go);
      b2[n] = *(const bf16x8*)(B2s + r * 32 + go);
    }
#pragma unroll
    for (int m = 0; m < 4; m++)
#pragma unroll
      for (int n = 0; n < 4; n++) {
        acc1[m][n] = __builtin_amdgcn_mfma_f32_16x16x32_bf16(ah[m], b1[n], acc1[m][n], 0, 0, 0);
        acc2[m][n] = __builtin_amdgcn_mfma_f32_16x16x32_bf16(ah[m], b2[n], acc2[m][n], 0, 0, 0);
      }
    __syncthreads();
  }
#pragma unroll
  for (int m = 0; m < 4; m++)
#pragma unroll
    for (int n = 0; n < 4; n++) {
      int gn = bn + wc + n * 16 + (l & 15);
#pragma unroll
      for (int j = 0; j < 4; j++) {
        int gm = bm + wr + m * 16 + (l >> 4) * 4 + j;
        float a = acc1[m][n][j];
        float s = a / (1.0f + __expf(-a));
        ffa[(size_t)gm * DFFF + gn] = f2b(s * acc2[m][n][j]);
      }
    }
}

// ======================= launch =======================
extern "C" void kernel_launch(void* const* d_in, const int* in_sizes, int n_in,
                              void* d_out, int out_size, void* d_ws, size_t ws_size,
                              hipStream_t stream) {
  const float* x   = (const float*)d_in[0];
  const float* nw  = (const float*)d_in[1];
  const float* wq  = (const float*)d_in[2];
  const float* wk  = (const float*)d_in[3];
  const float* wv  = (const float*)d_in[4];
  const float* wo  = (const float*)d_in[5];
  const float* lat = (const float*)d_in[6];
  const float* btp = (const float*)d_in[7];
  const float* asw = (const float*)d_in[8];
  const float* gw  = (const float*)d_in[9];
  const float* tn1 = (const float*)d_in[10];
  const float* tn2 = (const float*)d_in[11];
  const float* fnw = (const float*)d_in[12];
  const float* uw  = (const float*)d_in[13];
  const float* vw  = (const float*)d_in[14];
  const float* dw  = (const float*)d_in[15];
  float* out = (float*)d_out;
  char* W = (char*)d_ws;
  const size_t MB = 1u << 20;

  // layout (peak 40MB):
  // 0-8:   h / attn -> latP0(mixedS) -> nb+gb
  // 8-16:  q / apT -> spikesS -> s0+s1
  // 16-24: k -> lath -> hn+t1
  // 24-32: v -> latl -> h2 -> ffa
  // 32-40: latP1 -> gwb/uwT/vwT/dwT
  short* h_hi = (short*)(W);
  short* h_lo = (short*)(W + 4 * MB);
  short* attn_hi = h_hi;
  short* attn_lo = h_lo;
  float* latP0 = (float*)(W);
  short* nb = (short*)(W);
  float* gb = (float*)(W + 2 * MB);
  short* q_hi = (short*)(W + 8 * MB);
  short* q_lo = (short*)(W + 12 * MB);
  short* apT_hi = q_hi;
  short* apT_lo = q_lo;
  float* spikesS = (float*)(W + 8 * MB);
  float* s0 = (float*)(W + 8 * MB);
  float* s1 = (float*)(W + 12 * MB);
  short* k_hi = (short*)(W + 16 * MB);
  short* k_lo = (short*)(W + 20 * MB);
  short* lath = (short*)(W + 16 * MB);
  short* hn = (short*)(W + 16 * MB);
  short* t1 = (short*)(W + 20 * MB);
  short* v_hi = (short*)(W + 24 * MB);
  short* v_lo = (short*)(W + 28 * MB);
  short* latl = (short*)(W + 24 * MB);
  float* h2 = (float*)(W + 24 * MB);
  short* ffa = (short*)(W + 24 * MB);
  float* latP1 = (float*)(W + 32 * MB);
  short* gwb = (short*)(W + 32 * MB);
  short* uwT = gwb + 262144;
  short* vwT = uwT + 65536;
  short* dwT = vwT + 262144;

  short* wqh = (short*)out;
  short* wql = wqh + 262144;
  short* wkh = wql + 262144;
  short* wkl = wkh + 262144;
  short* wvh = wkl + 262144;
  short* wvl = wvh + 262144;
  short* woh = wvl + 262144;
  short* wol = woh + 262144;

  const int rows = BB * SS;  // 4096

  splitw4<<<dim3(256, 1, 4), 256, 0, stream>>>(wq, wk, wv, wo,
                                               wqh, wql, wkh, wkl, wvh, wvl, woh, wol);

  rmsnorm_hl<<<rows / 4, 256, 0, stream>>>(x, nw, h_hi, h_lo, rows);

  qkv_g<<<dim3(4, 32, 3), 256, 0, stream>>>(h_hi, h_lo,
                                            wqh, wql, wkh, wkl, wvh, wvl,
                                            q_hi, q_lo, k_hi, k_lo, v_hi, v_lo);

  attn_g<<<dim3(32, HH, BB), 256, 0, stream>>>(q_hi, q_lo, k_hi, k_lo, v_hi, v_lo,
                                               attn_hi, attn_lo);

  ggemm<true, 4, false><<<dim3(4, 32), 256, 0, stream>>>(
      attn_hi, attn_lo, woh, wol, nullptr, apT_hi, apT_lo, rows, DD, DD);

  splitlat<<<4096, 256, 0, stream>>>(lat, lath, latl);

  lat_g<<<dim3(4, 16, 4), 256, 0, stream>>>(lath, latl, apT_hi, apT_lo, latP0, latP1);

  // mixedS = latP0 + latP1 (layout-agnostic elementwise, in-place)
  sum2<<<(BB * DD * SS / 4) / 256, 256, 0, stream>>>(latP0, latP1, latP0);

  tsa_alif9<<<4, 64, 0, stream>>>(latP0, btp, asw, spikesS);
  fuse_h2<<<dim3(32, 8, 2), 256, 0, stream>>>(x, latP0, spikesS, h2);

  cvtb<<<256, 256, 0, stream>>>(gw, gwb, DD * DD);
  transp_cvt<<<dim3(4, 16), 256, 0, stream>>>(uw, uwT, DD, RANKK);
  transp_cvt<<<dim3(64, 4), 256, 0, stream>>>(vw, vwT, RANKK, 2 * DFFF);
  transp_cvt<<<dim3(16, 32), 256, 0, stream>>>(dw, dwT, DFFF, DD);

  const float* sin_ = h2;
  for (int lvl = 0; lvl < 11; lvl++) {
    int Sn = 1024 >> lvl;
    int r2 = BB * Sn;
    float* sout = (lvl & 1) ? s1 : s0;
    tree_reduce_b<<<(r2 + 3) / 4, 256, 0, stream>>>(sin_, tn1, nb, Sn);
    ggemm<false, 0, false><<<dim3(4, (r2 + 127) / 128), 256, 0, stream>>>(
        nb, nullptr, gwb, nullptr, nullptr, gb, nullptr, r2, DD, DD);
    tree_combine_b<<<(r2 + 3) / 4, 256, 0, stream>>>(gb, nb, sin_, tn2, sout, Sn);
    sin_ = sout;
  }

  h3hn_b<<<rows / 4, 256, 0, stream>>>(h2, sin_, fnw, out, hn);

  ggemm<false, 1, false><<<dim3(1, 32), 256, 0, stream>>>(
      hn, nullptr, uwT, nullptr, nullptr, t1, nullptr, rows, RANKK, DD);
  upgate_g<<<dim3(8, 32), 256, 0, stream>>>(t1, vwT, ffa);
  ggemm<false, 6, false><<<dim3(4, 32), 256, 0, stream>>>(
      ffa, nullptr, dwT, nullptr, out, out, nullptr, rows, DD, DFFF);
}

// Round 20
// 668.714 us; speedup vs baseline: 1.4266x; 1.4266x over previous
//
#include <hip/hip_runtime.h>
#include <math.h>

#define BB 2
#define SS 2048
#define DD 512
#define HH 8
#define HDD 64
#define RANKK 128
#define DFFF 1024

typedef short bf16x8 __attribute__((ext_vector_type(8)));
typedef float f32x4 __attribute__((ext_vector_type(4)));

__device__ __forceinline__ short f2b(float f) {
  union { float f; unsigned u; } v; v.f = f;
  unsigned r = v.u + 0x7FFF + ((v.u >> 16) & 1);
  return (short)(r >> 16);
}
__device__ __forceinline__ float b2f(short s) {
  union { unsigned u; float f; } v; v.u = ((unsigned)(unsigned short)s) << 16;
  return v.f;
}

__device__ __forceinline__ void gll16(const void* g, void* l) {
  __builtin_amdgcn_global_load_lds(
      (const __attribute__((address_space(1))) unsigned int*)g,
      (__attribute__((address_space(3))) unsigned int*)l, 16, 0, 0);
}

__device__ __forceinline__ float wsum(float v) {
#pragma unroll
  for (int off = 32; off > 0; off >>= 1) v += __shfl_xor(v, off, 64);
  return v;
}

// ---------------- 4-way weight split fp32 -> hi/lo bf16 ----------------
__global__ void splitw4(const float* __restrict__ w0, const float* __restrict__ w1,
                        const float* __restrict__ w2, const float* __restrict__ w3,
                        short* h0, short* l0_, short* h1, short* l1_,
                        short* h2_, short* l2_, short* h3_, short* l3_) {
  const int z = blockIdx.z;
  const float* in = (z == 0) ? w0 : (z == 1) ? w1 : (z == 2) ? w2 : w3;
  short* hi = (z == 0) ? h0 : (z == 1) ? h1 : (z == 2) ? h2_ : h3_;
  short* lo = (z == 0) ? l0_ : (z == 1) ? l1_ : (z == 2) ? l2_ : l3_;
  int i = (blockIdx.x * 256 + threadIdx.x) * 4;
  if (i >= DD * DD) return;
  float4 v = *(const float4*)(in + i);
  short4 h4, l4;
  h4.x = f2b(v.x); l4.x = f2b(v.x - b2f(h4.x));
  h4.y = f2b(v.y); l4.y = f2b(v.y - b2f(h4.y));
  h4.z = f2b(v.z); l4.z = f2b(v.z - b2f(h4.z));
  h4.w = f2b(v.w); l4.w = f2b(v.w - b2f(h4.w));
  *(short4*)(hi + i) = h4;
  *(short4*)(lo + i) = l4;
}

// ---------------- tril(lat) -> split bf16 hi/lo ----------------
__global__ void splitlat(const float* __restrict__ lat, short* __restrict__ hi,
                         short* __restrict__ lo) {
  int i = (blockIdx.x * 256 + threadIdx.x) * 4;
  int r = i >> 11;
  int c = i & 2047;
  float4 v = *(const float4*)(lat + i);
  if (c + 0 > r) v.x = 0.0f;
  if (c + 1 > r) v.y = 0.0f;
  if (c + 2 > r) v.z = 0.0f;
  if (c + 3 > r) v.w = 0.0f;
  short4 h4, l4;
  h4.x = f2b(v.x); l4.x = f2b(v.x - b2f(h4.x));
  h4.y = f2b(v.y); l4.y = f2b(v.y - b2f(h4.y));
  h4.z = f2b(v.z); l4.z = f2b(v.z - b2f(h4.z));
  h4.w = f2b(v.w); l4.w = f2b(v.w - b2f(h4.w));
  *(short4*)(hi + i) = h4;
  *(short4*)(lo + i) = l4;
}

// ---------------- fp32 -> bf16 single ----------------
__global__ void cvtb(const float* __restrict__ in, short* __restrict__ out, int n) {
  int i = (blockIdx.x * 256 + threadIdx.x) * 4;
  if (i >= n) return;
  float4 v = *(const float4*)(in + i);
  short4 o; o.x = f2b(v.x); o.y = f2b(v.y); o.z = f2b(v.z); o.w = f2b(v.w);
  *(short4*)(out + i) = o;
}

// ---------------- elementwise sum (in-place capable): o = a + b ----------------
__global__ void sum2(const float* __restrict__ a, const float* __restrict__ bq,
                     float* __restrict__ o) {
  int i = (blockIdx.x * 256 + threadIdx.x) * 4;
  float4 va = *(const float4*)(a + i);
  float4 vb = *(const float4*)(bq + i);
  float4 vo = {va.x + vb.x, va.y + vb.y, va.z + vb.z, va.w + vb.w};
  *(float4*)(o + i) = vo;
}

// ---------------- transpose + convert: in f32 [R][C] -> out bf16 [C][R] ----------------
__global__ void transp_cvt(const float* __restrict__ in, short* __restrict__ out,
                           int R, int C) {
  __shared__ float t[32][33];
  int c0 = blockIdx.x * 32, r0 = blockIdx.y * 32;
#pragma unroll
  for (int i = 0; i < 4; i++) {
    int idx = threadIdx.x + i * 256;
    int r = idx >> 5, c = idx & 31;
    t[r][c] = in[(size_t)(r0 + r) * C + c0 + c];
  }
  __syncthreads();
#pragma unroll
  for (int i = 0; i < 4; i++) {
    int idx = threadIdx.x + i * 256;
    int cc = idx >> 5, rr = idx & 31;
    out[(size_t)(c0 + cc) * R + r0 + rr] = f2b(t[rr][cc]);
  }
}

// ---------------- rmsnorm fp32 -> split bf16 ----------------
__global__ void rmsnorm_hl(const float* __restrict__ x, const float* __restrict__ w,
                           short* __restrict__ oh, short* __restrict__ ol, int rows) {
  int wid = blockIdx.x * 4 + (threadIdx.x >> 6);
  int lane = threadIdx.x & 63;
  if (wid >= rows) return;
  const float* xp = x + (size_t)wid * DD + lane * 8;
  float4 a = *(const float4*)xp;
  float4 b = *(const float4*)(xp + 4);
  float ss = a.x*a.x + a.y*a.y + a.z*a.z + a.w*a.w
           + b.x*b.x + b.y*b.y + b.z*b.z + b.w*b.w;
  ss = wsum(ss);
  float r = rsqrtf(ss * (1.0f / DD) + 1e-6f);
  const float* wp = w + lane * 8;
  float4 wa = *(const float4*)wp, wb = *(const float4*)(wp + 4);
  float o8[8] = {a.x*r*wa.x, a.y*r*wa.y, a.z*r*wa.z, a.w*r*wa.w,
                 b.x*r*wb.x, b.y*r*wb.y, b.z*r*wb.z, b.w*r*wb.w};
  short hv[8], lv[8];
#pragma unroll
  for (int i = 0; i < 8; i++) { hv[i] = f2b(o8[i]); lv[i] = f2b(o8[i] - b2f(hv[i])); }
  short* op = oh + (size_t)wid * DD + lane * 8;
  short* lp = ol + (size_t)wid * DD + lane * 8;
  *(short4*)op = make_short4(hv[0], hv[1], hv[2], hv[3]);
  *(short4*)(op + 4) = make_short4(hv[4], hv[5], hv[6], hv[7]);
  *(short4*)lp = make_short4(lv[0], lv[1], lv[2], lv[3]);
  *(short4*)(lp + 4) = make_short4(lv[4], lv[5], lv[6], lv[7]);
}

// ======================= unified bf16 GEMM, gll16 staging =======================
template <bool SPL, int OM, bool ROPE>
__global__ __launch_bounds__(256) void ggemm(const short* __restrict__ Ah_g,
                                             const short* __restrict__ Al_g,
                                             const short* __restrict__ Bh_g,
                                             const short* __restrict__ Bl_g,
                                             const float* __restrict__ ADD,
                                             void* __restrict__ C, void* __restrict__ C2,
                                             int M, int N, int K) {
  __shared__ short Ahs[128 * 32];
  __shared__ short Bhs[128 * 32];
  __shared__ short Als[SPL ? 128 * 32 : 8];
  __shared__ short Bls[SPL ? 128 * 32 : 8];
  const int tid = threadIdx.x, l = tid & 63, w = tid >> 6;
  const int wr = (w >> 1) * 64, wc = (w & 1) * 64;
  const int bm = blockIdx.y * 128, bn = blockIdx.x * 128;
  f32x4 acc[4][4] = {};
  for (int k0 = 0; k0 < K; k0 += 32) {
#pragma unroll
    for (int p = 0; p < 2; p++) {
      int row = p * 64 + (tid >> 2), g = tid & 3;
      int swz = (g ^ ((row >> 1) & 3)) * 8;
      gll16(Ah_g + (size_t)(bm + row) * K + k0 + swz, Ahs + p * 2048 + tid * 8);
      gll16(Bh_g + (size_t)(bn + row) * K + k0 + swz, Bhs + p * 2048 + tid * 8);
      if (SPL) {
        gll16(Al_g + (size_t)(bm + row) * K + k0 + swz, Als + p * 2048 + tid * 8);
        gll16(Bl_g + (size_t)(bn + row) * K + k0 + swz, Bls + p * 2048 + tid * 8);
      }
    }
    __syncthreads();
    bf16x8 ah[4], bh[4], al[4], bl[4];
#pragma unroll
    for (int m = 0; m < 4; m++) {
      int r = wr + m * 16 + (l & 15);
      int go = (((l >> 4) ^ ((r >> 1) & 3)) << 3);
      ah[m] = *(const bf16x8*)(Ahs + r * 32 + go);
      if (SPL) al[m] = *(const bf16x8*)(Als + r * 32 + go);
    }
#pragma unroll
    for (int n = 0; n < 4; n++) {
      int r = wc + n * 16 + (l & 15);
      int go = (((l >> 4) ^ ((r >> 1) & 3)) << 3);
      bh[n] = *(const bf16x8*)(Bhs + r * 32 + go);
      if (SPL) bl[n] = *(const bf16x8*)(Bls + r * 32 + go);
    }
#pragma unroll
    for (int m = 0; m < 4; m++)
#pragma unroll
      for (int n = 0; n < 4; n++) {
        acc[m][n] = __builtin_amdgcn_mfma_f32_16x16x32_bf16(ah[m], bh[n], acc[m][n], 0, 0, 0);
        if (SPL) {
          acc[m][n] = __builtin_amdgcn_mfma_f32_16x16x32_bf16(ah[m], bl[n], acc[m][n], 0, 0, 0);
          acc[m][n] = __builtin_amdgcn_mfma_f32_16x16x32_bf16(al[m], bh[n], acc[m][n], 0, 0, 0);
        }
      }
    __syncthreads();
  }
  const int ll = l & 15, lg4 = (l >> 4) * 4;
  if (ROPE) {
#pragma unroll
    for (int m = 0; m < 4; m++)
#pragma unroll
      for (int n = 0; n < 2; n++) {
        int i_ = n * 16 + ll;
        float inv = exp2f(-(float)i_ * (13.287712379549449f / 32.0f));
#pragma unroll
        for (int j = 0; j < 4; j++) {
          int gm = bm + wr + m * 16 + lg4 + j;
          int s = gm & (SS - 1);
          float ang = (float)s * inv;
          float sn, cs;
          sincosf(ang, &sn, &cs);
          float v1 = acc[m][n][j], v2 = acc[m][n + 2][j];
          acc[m][n][j]     = v1 * cs - v2 * sn;
          acc[m][n + 2][j] = v2 * cs + v1 * sn;
        }
      }
  }
#pragma unroll
  for (int m = 0; m < 4; m++)
#pragma unroll
    for (int n = 0; n < 4; n++) {
      int gn = bn + wc + n * 16 + ll;
#pragma unroll
      for (int j = 0; j < 4; j++) {
        int gm = bm + wr + m * 16 + lg4 + j;
        if (gm >= M || gn >= N) continue;
        float v = acc[m][n][j];
        if (OM == 0) {
          ((float*)C)[(size_t)gm * N + gn] = v;
        } else if (OM == 1) {
          ((short*)C)[(size_t)gm * N + gn] = f2b(v);
        } else if (OM == 6) {
          size_t off = (size_t)gm * N + gn;
          ((float*)C)[off] = v + ADD[off];
        } else {
          short hi = f2b(v);
          short lo = f2b(v - b2f(hi));
          int b = gm >> 11, s = gm & (SS - 1);
          int hh2 = gn >> 6, d = gn & 63;
          size_t off;
          if (OM == 2)      off = (((size_t)(b * HH + hh2)) * SS + s) * 64 + d;
          else if (OM == 3) off = (((size_t)(b * HH + hh2)) * 64 + d) * SS + s;
          else              off = ((size_t)(b * DD) + gn) * SS + s;
          ((short*)C)[off] = hi;
          ((short*)C2)[off] = lo;
        }
      }
    }
}

// ======================= fused QKV GEMM: z selects weight/output =======================
__global__ __launch_bounds__(256) void qkv_g(const short* __restrict__ Ah_g,
                                             const short* __restrict__ Al_g,
                                             const short* __restrict__ wh0, const short* __restrict__ wl0,
                                             const short* __restrict__ wh1, const short* __restrict__ wl1,
                                             const short* __restrict__ wh2, const short* __restrict__ wl2,
                                             short* __restrict__ c0h, short* __restrict__ c0l,
                                             short* __restrict__ c1h, short* __restrict__ c1l,
                                             short* __restrict__ c2h, short* __restrict__ c2l) {
  const int z = blockIdx.z;
  const short* Bh_g = (z == 0) ? wh0 : (z == 1) ? wh1 : wh2;
  const short* Bl_g = (z == 0) ? wl0 : (z == 1) ? wl1 : wl2;
  short* Ch = (z == 0) ? c0h : (z == 1) ? c1h : c2h;
  short* Cl = (z == 0) ? c0l : (z == 1) ? c1l : c2l;
  const int K = DD;
  __shared__ short Ahs[128 * 32];
  __shared__ short Bhs[128 * 32];
  __shared__ short Als[128 * 32];
  __shared__ short Bls[128 * 32];
  const int tid = threadIdx.x, l = tid & 63, w = tid >> 6;
  const int wr = (w >> 1) * 64, wc = (w & 1) * 64;
  const int bm = blockIdx.y * 128, bn = blockIdx.x * 128;
  f32x4 acc[4][4] = {};
  for (int k0 = 0; k0 < K; k0 += 32) {
#pragma unroll
    for (int p = 0; p < 2; p++) {
      int row = p * 64 + (tid >> 2), g = tid & 3;
      int swz = (g ^ ((row >> 1) & 3)) * 8;
      gll16(Ah_g + (size_t)(bm + row) * K + k0 + swz, Ahs + p * 2048 + tid * 8);
      gll16(Bh_g + (size_t)(bn + row) * K + k0 + swz, Bhs + p * 2048 + tid * 8);
      gll16(Al_g + (size_t)(bm + row) * K + k0 + swz, Als + p * 2048 + tid * 8);
      gll16(Bl_g + (size_t)(bn + row) * K + k0 + swz, Bls + p * 2048 + tid * 8);
    }
    __syncthreads();
    bf16x8 ah[4], bh[4], al[4], bl[4];
#pragma unroll
    for (int m = 0; m < 4; m++) {
      int r = wr + m * 16 + (l & 15);
      int go = (((l >> 4) ^ ((r >> 1) & 3)) << 3);
      ah[m] = *(const bf16x8*)(Ahs + r * 32 + go);
      al[m] = *(const bf16x8*)(Als + r * 32 + go);
    }
#pragma unroll
    for (int n = 0; n < 4; n++) {
      int r = wc + n * 16 + (l & 15);
      int go = (((l >> 4) ^ ((r >> 1) & 3)) << 3);
      bh[n] = *(const bf16x8*)(Bhs + r * 32 + go);
      bl[n] = *(const bf16x8*)(Bls + r * 32 + go);
    }
#pragma unroll
    for (int m = 0; m < 4; m++)
#pragma unroll
      for (int n = 0; n < 4; n++) {
        acc[m][n] = __builtin_amdgcn_mfma_f32_16x16x32_bf16(ah[m], bh[n], acc[m][n], 0, 0, 0);
        acc[m][n] = __builtin_amdgcn_mfma_f32_16x16x32_bf16(ah[m], bl[n], acc[m][n], 0, 0, 0);
        acc[m][n] = __builtin_amdgcn_mfma_f32_16x16x32_bf16(al[m], bh[n], acc[m][n], 0, 0, 0);
      }
    __syncthreads();
  }
  const int ll = l & 15, lg4 = (l >> 4) * 4;
  if (z < 2) {  // RoPE on q, k
#pragma unroll
    for (int m = 0; m < 4; m++)
#pragma unroll
      for (int n = 0; n < 2; n++) {
        int i_ = n * 16 + ll;
        float inv = exp2f(-(float)i_ * (13.287712379549449f / 32.0f));
#pragma unroll
        for (int j = 0; j < 4; j++) {
          int gm = bm + wr + m * 16 + lg4 + j;
          int s = gm & (SS - 1);
          float ang = (float)s * inv;
          float sn, cs;
          sincosf(ang, &sn, &cs);
          float v1 = acc[m][n][j], v2 = acc[m][n + 2][j];
          acc[m][n][j]     = v1 * cs - v2 * sn;
          acc[m][n + 2][j] = v2 * cs + v1 * sn;
        }
      }
  }
#pragma unroll
  for (int m = 0; m < 4; m++)
#pragma unroll
    for (int n = 0; n < 4; n++) {
      int gn = bn + wc + n * 16 + ll;
#pragma unroll
      for (int j = 0; j < 4; j++) {
        int gm = bm + wr + m * 16 + lg4 + j;
        float v = acc[m][n][j];
        short hi = f2b(v);
        short lo = f2b(v - b2f(hi));
        int b = gm >> 11, s = gm & (SS - 1);
        int hh2 = gn >> 6, d = gn & 63;
        size_t off = (z < 2) ? ((((size_t)(b * HH + hh2)) * SS + s) * 64 + d)
                             : ((((size_t)(b * HH + hh2)) * 64 + d) * SS + s);
        Ch[off] = hi;
        Cl[off] = lo;
      }
    }
}

// ======================= lateral GEMM: pre-split A, split-K=2, rotated output =======================
__global__ __launch_bounds__(256) void lat_g(const short* __restrict__ lath,
                                             const short* __restrict__ latl,
                                             const short* __restrict__ bTh,
                                             const short* __restrict__ bTl,
                                             float* __restrict__ P0,
                                             float* __restrict__ P1) {
  const int zb = blockIdx.z >> 1;
  const int half = blockIdx.z & 1;
  bTh += (size_t)zb * DD * SS;
  bTl += (size_t)zb * DD * SS;
  float* Cc = (half == 0 ? P0 : P1) + (size_t)zb * DD * SS;
  __shared__ short Ah[128 * 32];
  __shared__ short Al[128 * 32];
  __shared__ short Bh[128 * 32];
  __shared__ short Bl[128 * 32];
  const int tid = threadIdx.x, l = tid & 63, w = tid >> 6;
  const int wr = (w >> 1) * 64, wc = (w & 1) * 64;
  const int bm = blockIdx.y * 128, bn = blockIdx.x * 128;
  const int T = blockIdx.y + 1;
  const int h0 = (T + 1) >> 1;
  const int kbeg = (half == 0) ? 0 : h0 * 128;
  const int kend = (half == 0) ? h0 * 128 : T * 128;
  f32x4 acc[4][4] = {};
  const int ll = l & 15, lg4 = (l >> 4) * 4;
  for (int k0 = kbeg; k0 < kend; k0 += 32) {
#pragma unroll
    for (int p = 0; p < 2; p++) {
      int row = p * 64 + (tid >> 2), g = tid & 3;
      int swz = (g ^ ((row >> 1) & 3)) * 8;
      gll16(bTh + (size_t)(bn + row) * SS + k0 + swz, Bh + p * 2048 + tid * 8);
      gll16(bTl + (size_t)(bn + row) * SS + k0 + swz, Bl + p * 2048 + tid * 8);
      gll16(lath + (size_t)(bm + row) * SS + k0 + swz, Ah + p * 2048 + tid * 8);
      gll16(latl + (size_t)(bm + row) * SS + k0 + swz, Al + p * 2048 + tid * 8);
    }
    __syncthreads();
    bf16x8 ah[4], bh[4], al[4], bl[4];
#pragma unroll
    for (int m = 0; m < 4; m++) {
      int r = wr + m * 16 + (l & 15);
      int go = (((l >> 4) ^ ((r >> 1) & 3)) << 3);
      ah[m] = *(const bf16x8*)(Ah + r * 32 + go);
      al[m] = *(const bf16x8*)(Al + r * 32 + go);
    }
#pragma unroll
    for (int n = 0; n < 4; n++) {
      int r = wc + n * 16 + (l & 15);
      int go = (((l >> 4) ^ ((r >> 1) & 3)) << 3);
      bh[n] = *(const bf16x8*)(Bh + r * 32 + go);
      bl[n] = *(const bf16x8*)(Bl + r * 32 + go);
    }
#pragma unroll
    for (int m = 0; m < 4; m++)
#pragma unroll
      for (int n = 0; n < 4; n++) {
        acc[m][n] = __builtin_amdgcn_mfma_f32_16x16x32_bf16(ah[m], bh[n], acc[m][n], 0, 0, 0);
        acc[m][n] = __builtin_amdgcn_mfma_f32_16x16x32_bf16(ah[m], bl[n], acc[m][n], 0, 0, 0);
        acc[m][n] = __builtin_amdgcn_mfma_f32_16x16x32_bf16(al[m], bh[n], acc[m][n], 0, 0, 0);
      }
    __syncthreads();
  }
#pragma unroll
  for (int m = 0; m < 4; m++)
#pragma unroll
    for (int n = 0; n < 4; n++) {
      int gn = bn + wc + n * 16 + ll;
#pragma unroll
      for (int j = 0; j < 4; j++) {
        int gm = bm + wr + m * 16 + lg4 + j;
        size_t off = ((size_t)((gm >> 5) * 512 + gn)) * 32 + ((gm + gn) & 31);
        Cc[off] = acc[m][n][j];
      }
    }
}

// ======================= flash attention (P hi-only PV) =======================
__global__ __launch_bounds__(256) void attn_g(const short* __restrict__ qh,
                                              const short* __restrict__ ql,
                                              const short* __restrict__ kh,
                                              const short* __restrict__ kl,
                                              const short* __restrict__ vh,
                                              const short* __restrict__ vl,
                                              short* __restrict__ aho,
                                              short* __restrict__ alo) {
  const int h = blockIdx.y, b = blockIdx.z;
  const int qt = (b == 0) ? (int)blockIdx.x : 31 - (int)blockIdx.x;
  const int q0 = qt * 64;
  const int tid = threadIdx.x, w = tid >> 6, l = tid & 63;
  const int lg = l >> 4, ll = l & 15;
  __shared__ short Kh[64 * 64], Kl[64 * 64];
  __shared__ short Vh[64 * 64], Vl[64 * 64];
  __shared__ short Ph[64 * 64];
  const size_t bh = (size_t)(b * HH + h);

  const int qr = q0 + w * 16 + ll;
  const short* qbh = qh + (bh * SS + qr) * 64;
  const short* qbl = ql + (bh * SS + qr) * 64;
  bf16x8 qfh[2], qfl[2];
#pragma unroll
  for (int ks = 0; ks < 2; ks++) {
    qfh[ks] = *(const bf16x8*)(qbh + (ks * 4 + lg) * 8);
    qfl[ks] = *(const bf16x8*)(qbl + (ks * 4 + lg) * 8);
  }

  f32x4 o[4] = {};
  float mrow[4] = {-1e30f, -1e30f, -1e30f, -1e30f};
  float lsum[4] = {};
  const int qrow0 = q0 + w * 16 + lg * 4;
  const int ntiles = qt + 1;

  for (int kt = 0; kt < ntiles; kt++) {
#pragma unroll
    for (int p = 0; p < 2; p++) {
      int row = p * 32 + (tid >> 3), g = tid & 7;
      int sw = ((g ^ (row & 7)) << 3);
      size_t krow = (bh * SS + kt * 64 + row) * 64;
      size_t vrow = (bh * 64 + row) * SS + kt * 64;
      gll16(kh + krow + sw, Kh + p * 2048 + tid * 8);
      gll16(kl + krow + sw, Kl + p * 2048 + tid * 8);
      gll16(vh + vrow + sw, Vh + p * 2048 + tid * 8);
      gll16(vl + vrow + sw, Vl + p * 2048 + tid * 8);
    }
    __syncthreads();

    f32x4 sv[4] = {};
#pragma unroll
    for (int nf = 0; nf < 4; nf++) {
      int r = nf * 16 + ll;
#pragma unroll
      for (int ks = 0; ks < 2; ks++) {
        int g = (ks * 4 + lg) ^ (r & 7);
        bf16x8 khf = *(const bf16x8*)(Kh + r * 64 + g * 8);
        bf16x8 klf = *(const bf16x8*)(Kl + r * 64 + g * 8);
        sv[nf] = __builtin_amdgcn_mfma_f32_16x16x32_bf16(qfh[ks], khf, sv[nf], 0, 0, 0);
        sv[nf] = __builtin_amdgcn_mfma_f32_16x16x32_bf16(qfh[ks], klf, sv[nf], 0, 0, 0);
        sv[nf] = __builtin_amdgcn_mfma_f32_16x16x32_bf16(qfl[ks], khf, sv[nf], 0, 0, 0);
      }
    }
#pragma unroll
    for (int nf = 0; nf < 4; nf++) {
      int kpos = kt * 64 + nf * 16 + ll;
#pragma unroll
      for (int j = 0; j < 4; j++) {
        float v = sv[nf][j] * 0.125f;
        sv[nf][j] = (kpos > qrow0 + j) ? -1e30f : v;
      }
    }
    float cf[4];
#pragma unroll
    for (int j = 0; j < 4; j++) {
      float r = fmaxf(fmaxf(sv[0][j], sv[1][j]), fmaxf(sv[2][j], sv[3][j]));
      r = fmaxf(r, __shfl_xor(r, 1)); r = fmaxf(r, __shfl_xor(r, 2));
      r = fmaxf(r, __shfl_xor(r, 4)); r = fmaxf(r, __shfl_xor(r, 8));
      float mn = fmaxf(mrow[j], r);
      cf[j] = __expf(mrow[j] - mn);
      mrow[j] = mn;
    }
    float ps[4] = {};
#pragma unroll
    for (int nf = 0; nf < 4; nf++)
#pragma unroll
      for (int j = 0; j < 4; j++) {
        float p = __expf(sv[nf][j] - mrow[j]);
        sv[nf][j] = p;
        ps[j] += p;
      }
#pragma unroll
    for (int j = 0; j < 4; j++) {
      float r = ps[j];
      r += __shfl_xor(r, 1); r += __shfl_xor(r, 2);
      r += __shfl_xor(r, 4); r += __shfl_xor(r, 8);
      lsum[j] = lsum[j] * cf[j] + r;
    }
#pragma unroll
    for (int nf = 0; nf < 4; nf++)
#pragma unroll
      for (int j = 0; j < 4; j++) o[nf][j] *= cf[j];
    // write P (hi only)
#pragma unroll
    for (int nf = 0; nf < 4; nf++)
#pragma unroll
      for (int j = 0; j < 4; j++) {
        int rowP = w * 16 + lg * 4 + j;
        int col = nf * 16 + ll;
        int off = rowP * 64 + (((col >> 3) ^ (rowP & 7)) << 3) + (col & 7);
        Ph[off] = f2b(sv[nf][j]);
      }
    __syncthreads();
    bf16x8 pfh[2];
    {
      int rowA = w * 16 + ll;
#pragma unroll
      for (int ks = 0; ks < 2; ks++) {
        int g = (ks * 4 + lg) ^ (rowA & 7);
        pfh[ks] = *(const bf16x8*)(Ph + rowA * 64 + g * 8);
      }
    }
#pragma unroll
    for (int nf = 0; nf < 4; nf++) {
      int r = nf * 16 + ll;
#pragma unroll
      for (int ks = 0; ks < 2; ks++) {
        int g = (ks * 4 + lg) ^ (r & 7);
        bf16x8 vhf = *(const bf16x8*)(Vh + r * 64 + g * 8);
        bf16x8 vlf = *(const bf16x8*)(Vl + r * 64 + g * 8);
        o[nf] = __builtin_amdgcn_mfma_f32_16x16x32_bf16(pfh[ks], vhf, o[nf], 0, 0, 0);
        o[nf] = __builtin_amdgcn_mfma_f32_16x16x32_bf16(pfh[ks], vlf, o[nf], 0, 0, 0);
      }
    }
    __syncthreads();
  }
  float inv[4];
#pragma unroll
  for (int j = 0; j < 4; j++) inv[j] = 1.0f / lsum[j];
#pragma unroll
  for (int nf = 0; nf < 4; nf++)
#pragma unroll
    for (int j = 0; j < 4; j++) {
      float v = o[nf][j] * inv[j];
      short hi = f2b(v);
      size_t off = ((size_t)(b * SS + qrow0 + j)) * DD + h * HDD + nf * 16 + ll;
      aho[off] = hi;
      alo[off] = f2b(v - b2f(hi));
    }
}

// ======================= ALIF scan: single-stream async-LDS (latency-floor bound) =======================
#define ACH 32
__global__ __launch_bounds__(64) void tsa_alif8(const float* __restrict__ mixedS,
                                                const float* __restrict__ bt,
                                                const float* __restrict__ asw,
                                                float* __restrict__ spikesS) {
  __shared__ float lds[2][ACH * 64];  // 16 KB
  const int t = threadIdx.x;
  const int tid = blockIdx.x * 64 + t;
  const int b = tid >> 9, d = tid & 511;
  const int d0 = d & ~63;
  const float btd = bt[d], asd = asw[d];
  const float C = 36.06737602222409f;  // 25 * log2(e)
  const float bt36 = btd * C, as36 = asd * C;
  const float bt99 = 0.99f * btd, as99 = 0.99f * asd;
  const size_t bbase = (size_t)b * DD * SS;
  const float* mp = mixedS + bbase;
  float* sp = spikesS + bbase;
  {
    const float* g0 = mp + (size_t)d0 * 32;
#pragma unroll
    for (int i = 0; i < 8; i++) gll16(g0 + i * 256 + t * 4, &lds[0][i * 256 + t * 4]);
  }
  float vR = 0.0f, ad = 0.0f;
  for (int c = 0; c < SS / ACH; c++) {
    const int cur = c & 1;
    __syncthreads();
    if (c + 1 < SS / ACH) {
      const float* gq = mp + ((size_t)((c + 1) * 512 + d0)) * 32;
#pragma unroll
      for (int i = 0; i < 8; i++) gll16(gq + i * 256 + t * 4, &lds[cur ^ 1][i * 256 + t * 4]);
    }
    float m[ACH];
#pragma unroll
    for (int j = 0; j < ACH; j++) m[j] = lds[cur][t * 32 + ((j + t) & 31)];
    vR += m[0];
    float sO[ACH];
#pragma unroll
    for (int j = 0; j < ACH; j++) {
      float thC = fmaf(ad, as36, bt36);
      float th99 = fmaf(ad, as99, bt99);
      float arg = fmaf(vR, -C, thC);
      float e = exp2f(arg);
      float s = __builtin_amdgcn_rcpf(1.0f + e);
      sO[j] = s;
      float pre = (j + 1 < ACH) ? fmaf(0.99f, vR, m[j + 1]) : (0.99f * vR);
      vR = fmaf(-th99, s, pre);
      ad = fmaf(0.95f, ad, s);
    }
#pragma unroll
    for (int j = 0; j < ACH; j++) lds[cur][t * 32 + ((j + t) & 31)] = sO[j];
    __syncthreads();
    float* so = sp + ((size_t)(c * 512 + d0)) * 32;
#pragma unroll
    for (int i = 0; i < 8; i++) {
      float4 v4 = *(const float4*)&lds[cur][i * 256 + t * 4];
      *(float4*)(so + i * 256 + t * 4) = v4;
    }
  }
}

// ======================= h2 = x + mixedS^T + spikes^T (rotated layouts) =======================
__global__ __launch_bounds__(256) void fuse_h2(const float* __restrict__ x,
                                               const float* __restrict__ mixedS,
                                               const float* __restrict__ spikesS,
                                               float* __restrict__ h2) {
  const int s0 = blockIdx.x * 64, d0 = blockIdx.y * 64, b = blockIdx.z;
  __shared__ float t[64][65];
  const int dl = threadIdx.x >> 2;
  const int grp = threadIdx.x & 3;
  const size_t bbase = (size_t)b * DD * SS;
#pragma unroll
  for (int i = 0; i < 16; i++) {
    int sl = grp * 16 + i;
    int sg = s0 + sl;
    size_t off = bbase + ((size_t)((sg >> 5) * 512 + d0 + dl)) * 32 + ((sg + dl) & 31);
    t[dl][sl] = mixedS[off] + spikesS[off];
  }
  __syncthreads();
#pragma unroll
  for (int k = 0; k < 4; k++) {
    int sl = threadIdx.x >> 2;
    int dl2 = (threadIdx.x & 3) * 16 + k * 4;
    size_t off = ((size_t)(b * SS + s0 + sl)) * DD + d0 + dl2;
    float4 xv = *(const float4*)(x + off);
    float4 o;
    o.x = xv.x + t[dl2 + 0][sl];
    o.y = xv.y + t[dl2 + 1][sl];
    o.z = xv.z + t[dl2 + 2][sl];
    o.w = xv.w + t[dl2 + 3][sl];
    *(float4*)(h2 + off) = o;
  }
}

// ======================= tree kernels =======================
__global__ void tree_reduce_b(const float* __restrict__ sin_, const float* __restrict__ tn1,
                              short* __restrict__ nb, int Sn) {
  int wid = blockIdx.x * 4 + (threadIdx.x >> 6);
  int lane = threadIdx.x & 63;
  int rows = BB * Sn;
  if (wid >= rows) return;
  int b = wid / Sn, j = wid - b * Sn;
  const float* r0 = sin_ + ((size_t)(b * 2 * Sn + 2 * j)) * DD + lane * 8;
  const float* r1 = r0 + DD;
  float4 a0 = *(const float4*)r0, a1 = *(const float4*)(r0 + 4);
  float4 b0 = *(const float4*)r1, b1 = *(const float4*)(r1 + 4);
  float ra[8] = {a0.x + b0.x, a0.y + b0.y, a0.z + b0.z, a0.w + b0.w,
                 a1.x + b1.x, a1.y + b1.y, a1.z + b1.z, a1.w + b1.w};
  float ss = 0.0f;
#pragma unroll
  for (int i = 0; i < 8; i++) ss += ra[i] * ra[i];
  ss = wsum(ss);
  float rms = rsqrtf(ss * (1.0f / DD) + 1e-6f);
  const float* wp = tn1 + lane * 8;
  float4 wa = *(const float4*)wp, wb = *(const float4*)(wp + 4);
  float wv8[8] = {wa.x, wa.y, wa.z, wa.w, wb.x, wb.y, wb.z, wb.w};
  short* np = nb + (size_t)wid * DD + lane * 8;
  short4 n0, n1;
  n0.x = f2b(ra[0]*rms*wv8[0]); n0.y = f2b(ra[1]*rms*wv8[1]);
  n0.z = f2b(ra[2]*rms*wv8[2]); n0.w = f2b(ra[3]*rms*wv8[3]);
  n1.x = f2b(ra[4]*rms*wv8[4]); n1.y = f2b(ra[5]*rms*wv8[5]);
  n1.z = f2b(ra[6]*rms*wv8[6]); n1.w = f2b(ra[7]*rms*wv8[7]);
  *(short4*)np = n0;
  *(short4*)(np + 4) = n1;
}

__global__ void tree_combine_b(const float* __restrict__ g, const short* __restrict__ nb,
                               const float* __restrict__ sin_, const float* __restrict__ tn2,
                               float* __restrict__ sout, int Sn) {
  int wid = blockIdx.x * 4 + (threadIdx.x >> 6);
  int lane = threadIdx.x & 63;
  int rows = BB * Sn;
  if (wid >= rows) return;
  int b = wid / Sn, j = wid - b * Sn;
  const float* r0 = sin_ + ((size_t)(b * 2 * Sn + 2 * j)) * DD + lane * 8;
  const float* r1 = r0 + DD;
  float4 a0 = *(const float4*)r0, a1 = *(const float4*)(r0 + 4);
  float4 b0 = *(const float4*)r1, b1 = *(const float4*)(r1 + 4);
  float res[8] = {0.5f*(a0.x + b0.x), 0.5f*(a0.y + b0.y), 0.5f*(a0.z + b0.z), 0.5f*(a0.w + b0.w),
                  0.5f*(a1.x + b1.x), 0.5f*(a1.y + b1.y), 0.5f*(a1.z + b1.z), 0.5f*(a1.w + b1.w)};
  size_t base = (size_t)wid * DD + lane * 8;
  float t[8];
  float ss = 0.0f;
#pragma unroll
  for (int i = 0; i < 8; i++) {
    float gg = 1.0f / (1.0f + expf(-g[base + i]));
    float tv = gg * b2f(nb[base + i]) + (1.0f - gg) * res[i];
    t[i] = tv;
    ss += tv * tv;
  }
  ss = wsum(ss);
  float rms = rsqrtf(ss * (1.0f / DD) + 1e-6f);
#pragma unroll
  for (int i = 0; i < 8; i++) sout[base + i] = t[i] * rms * tn2[lane * 8 + i];
}

// h3 = h2 + root -> out fp32; hn = rmsnorm(h3) -> bf16
__global__ void h3hn_b(const float* __restrict__ h2, const float* __restrict__ root,
                       const float* __restrict__ fw, float* __restrict__ h3,
                       short* __restrict__ hn) {
  int wid = blockIdx.x * 4 + (threadIdx.x >> 6);
  int lane = threadIdx.x & 63;
  int b = wid >> 11;
  size_t base = (size_t)wid * DD + lane * 8;
  const float* rp = root + (size_t)b * DD + lane * 8;
  float t[8];
  float ss = 0.0f;
#pragma unroll
  for (int i = 0; i < 8; i++) {
    float tv = h2[base + i] + rp[i];
    t[i] = tv;
    ss += tv * tv;
    h3[base + i] = tv;
  }
  ss = wsum(ss);
  float rms = rsqrtf(ss * (1.0f / DD) + 1e-6f);
#pragma unroll
  for (int i = 0; i < 8; i++) hn[base + i] = f2b(t[i] * rms * fw[lane * 8 + i]);
}

// ======================= upgate =======================
__global__ __launch_bounds__(256) void upgate_g(const short* __restrict__ A,
                                                const short* __restrict__ Bv,
                                                short* __restrict__ ffa) {
  __shared__ short Ahs[128 * 32];
  __shared__ short B1s[128 * 32];
  __shared__ short B2s[128 * 32];
  const int tid = threadIdx.x, l = tid & 63, w = tid >> 6;
  const int wr = (w >> 1) * 64, wc = (w & 1) * 64;
  const int bm = blockIdx.y * 128, bn = blockIdx.x * 128;
  f32x4 acc1[4][4] = {}, acc2[4][4] = {};
  for (int k0 = 0; k0 < RANKK; k0 += 32) {
#pragma unroll
    for (int p = 0; p < 2; p++) {
      int row = p * 64 + (tid >> 2), g = tid & 3;
      int swz = (g ^ ((row >> 1) & 3)) * 8;
      gll16(A + (size_t)(bm + row) * RANKK + k0 + swz, Ahs + p * 2048 + tid * 8);
      gll16(Bv + (size_t)(bn + row) * RANKK + k0 + swz, B1s + p * 2048 + tid * 8);
      gll16(Bv + (size_t)(DFFF + bn + row) * RANKK + k0 + swz, B2s + p * 2048 + tid * 8);
    }
    __syncthreads();
    bf16x8 ah[4], b1[4], b2[4];
#pragma unroll
    for (int m = 0; m < 4; m++) {
      int r = wr + m * 16 + (l & 15);
      int go = (((l >> 4) ^ ((r >> 1) & 3)) << 3);
      ah[m] = *(const bf16x8*)(Ahs + r * 32 + go);
    }
#pragma unroll
    for (int n = 0; n < 4; n++) {
      int r = wc + n * 16 + (l & 15);
      int go = (((l >> 4) ^ ((r >> 1) & 3)) << 3);
      b1[n] = *(const bf16x8*)(B1s + r * 32 + go);
      b2[n] = *(const bf16x8*)(B2s + r * 32 + go);
    }
#pragma unroll
    for (int m = 0; m < 4; m++)
#pragma unroll
      for (int n = 0; n < 4; n++) {
        acc1[m][n] = __builtin_amdgcn_mfma_f32_16x16x32_bf16(ah[m], b1[n], acc1[m][n], 0, 0, 0);
        acc2[m][n] = __builtin_amdgcn_mfma_f32_16x16x32_bf16(ah[m], b2[n], acc2[m][n], 0, 0, 0);
      }
    __syncthreads();
  }
#pragma unroll
  for (int m = 0; m < 4; m++)
#pragma unroll
    for (int n = 0; n < 4; n++) {
      int gn = bn + wc + n * 16 + (l & 15);
#pragma unroll
      for (int j = 0; j < 4; j++) {
        int gm = bm + wr + m * 16 + (l >> 4) * 4 + j;
        float a = acc1[m][n][j];
        float s = a / (1.0f + __expf(-a));
        ffa[(size_t)gm * DFFF + gn] = f2b(s * acc2[m][n][j]);
      }
    }
}

// ======================= launch =======================
extern "C" void kernel_launch(void* const* d_in, const int* in_sizes, int n_in,
                              void* d_out, int out_size, void* d_ws, size_t ws_size,
                              hipStream_t stream) {
  const float* x   = (const float*)d_in[0];
  const float* nw  = (const float*)d_in[1];
  const float* wq  = (const float*)d_in[2];
  const float* wk  = (const float*)d_in[3];
  const float* wv  = (const float*)d_in[4];
  const float* wo  = (const float*)d_in[5];
  const float* lat = (const float*)d_in[6];
  const float* btp = (const float*)d_in[7];
  const float* asw = (const float*)d_in[8];
  const float* gw  = (const float*)d_in[9];
  const float* tn1 = (const float*)d_in[10];
  const float* tn2 = (const float*)d_in[11];
  const float* fnw = (const float*)d_in[12];
  const float* uw  = (const float*)d_in[13];
  const float* vw  = (const float*)d_in[14];
  const float* dw  = (const float*)d_in[15];
  float* out = (float*)d_out;
  char* W = (char*)d_ws;
  const size_t MB = 1u << 20;

  // layout (peak 40MB):
  // 0-8:   h / attn -> latP0(mixedS) -> nb+gb
  // 8-16:  q / apT -> spikesS -> s0+s1
  // 16-24: k -> lath -> hn+t1
  // 24-32: v -> latl -> h2 -> ffa
  // 32-40: latP1 -> gwb/uwT/vwT/dwT
  short* h_hi = (short*)(W);
  short* h_lo = (short*)(W + 4 * MB);
  short* attn_hi = h_hi;
  short* attn_lo = h_lo;
  float* latP0 = (float*)(W);
  short* nb = (short*)(W);
  float* gb = (float*)(W + 2 * MB);
  short* q_hi = (short*)(W + 8 * MB);
  short* q_lo = (short*)(W + 12 * MB);
  short* apT_hi = q_hi;
  short* apT_lo = q_lo;
  float* spikesS = (float*)(W + 8 * MB);
  float* s0 = (float*)(W + 8 * MB);
  float* s1 = (float*)(W + 12 * MB);
  short* k_hi = (short*)(W + 16 * MB);
  short* k_lo = (short*)(W + 20 * MB);
  short* lath = (short*)(W + 16 * MB);
  short* hn = (short*)(W + 16 * MB);
  short* t1 = (short*)(W + 20 * MB);
  short* v_hi = (short*)(W + 24 * MB);
  short* v_lo = (short*)(W + 28 * MB);
  short* latl = (short*)(W + 24 * MB);
  float* h2 = (float*)(W + 24 * MB);
  short* ffa = (short*)(W + 24 * MB);
  float* latP1 = (float*)(W + 32 * MB);
  short* gwb = (short*)(W + 32 * MB);
  short* uwT = gwb + 262144;
  short* vwT = uwT + 65536;
  short* dwT = vwT + 262144;

  short* wqh = (short*)out;
  short* wql = wqh + 262144;
  short* wkh = wql + 262144;
  short* wkl = wkh + 262144;
  short* wvh = wkl + 262144;
  short* wvl = wvh + 262144;
  short* woh = wvl + 262144;
  short* wol = woh + 262144;

  const int rows = BB * SS;  // 4096

  splitw4<<<dim3(256, 1, 4), 256, 0, stream>>>(wq, wk, wv, wo,
                                               wqh, wql, wkh, wkl, wvh, wvl, woh, wol);

  rmsnorm_hl<<<rows / 4, 256, 0, stream>>>(x, nw, h_hi, h_lo, rows);

  qkv_g<<<dim3(4, 32, 3), 256, 0, stream>>>(h_hi, h_lo,
                                            wqh, wql, wkh, wkl, wvh, wvl,
                                            q_hi, q_lo, k_hi, k_lo, v_hi, v_lo);

  attn_g<<<dim3(32, HH, BB), 256, 0, stream>>>(q_hi, q_lo, k_hi, k_lo, v_hi, v_lo,
                                               attn_hi, attn_lo);

  ggemm<true, 4, false><<<dim3(4, 32), 256, 0, stream>>>(
      attn_hi, attn_lo, woh, wol, nullptr, apT_hi, apT_lo, rows, DD, DD);

  splitlat<<<4096, 256, 0, stream>>>(lat, lath, latl);

  lat_g<<<dim3(4, 16, 4), 256, 0, stream>>>(lath, latl, apT_hi, apT_lo, latP0, latP1);

  // mixedS = latP0 + latP1 (layout-agnostic elementwise, in-place)
  sum2<<<(BB * DD * SS / 4) / 256, 256, 0, stream>>>(latP0, latP1, latP0);

  tsa_alif8<<<16, 64, 0, stream>>>(latP0, btp, asw, spikesS);
  fuse_h2<<<dim3(32, 8, 2), 256, 0, stream>>>(x, latP0, spikesS, h2);

  cvtb<<<256, 256, 0, stream>>>(gw, gwb, DD * DD);
  transp_cvt<<<dim3(4, 16), 256, 0, stream>>>(uw, uwT, DD, RANKK);
  transp_cvt<<<dim3(64, 4), 256, 0, stream>>>(vw, vwT, RANKK, 2 * DFFF);
  transp_cvt<<<dim3(16, 32), 256, 0, stream>>>(dw, dwT, DFFF, DD);

  const float* sin_ = h2;
  for (int lvl = 0; lvl < 11; lvl++) {
    int Sn = 1024 >> lvl;
    int r2 = BB * Sn;
    float* sout = (lvl & 1) ? s1 : s0;
    tree_reduce_b<<<(r2 + 3) / 4, 256, 0, stream>>>(sin_, tn1, nb, Sn);
    ggemm<false, 0, false><<<dim3(4, (r2 + 127) / 128), 256, 0, stream>>>(
        nb, nullptr, gwb, nullptr, nullptr, gb, nullptr, r2, DD, DD);
    tree_combine_b<<<(r2 + 3) / 4, 256, 0, stream>>>(gb, nb, sin_, tn2, sout, Sn);
    sin_ = sout;
  }

  h3hn_b<<<rows / 4, 256, 0, stream>>>(h2, sin_, fnw, out, hn);

  ggemm<false, 1, false><<<dim3(1, 32), 256, 0, stream>>>(
      hn, nullptr, uwT, nullptr, nullptr, t1, nullptr, rows, RANKK, DD);
  upgate_g<<<dim3(8, 32), 256, 0, stream>>>(t1, vwT, ffa);
  ggemm<false, 6, false><<<dim3(4, 32), 256, 0, stream>>>(
      ffa, nullptr, dwT, nullptr, out, out, nullptr, rows, DD, DFFF);
}

// Round 21
// 653.279 us; speedup vs baseline: 1.4603x; 1.0236x over previous
//
#include <hip/hip_runtime.h>
#include <math.h>

#define BB 2
#define SS 2048
#define DD 512
#define HH 8
#define HDD 64
#define RANKK 128
#define DFFF 1024

typedef short bf16x8 __attribute__((ext_vector_type(8)));
typedef float f32x4 __attribute__((ext_vector_type(4)));

__device__ __forceinline__ short f2b(float f) {
  union { float f; unsigned u; } v; v.f = f;
  unsigned r = v.u + 0x7FFF + ((v.u >> 16) & 1);
  return (short)(r >> 16);
}
__device__ __forceinline__ float b2f(short s) {
  union { unsigned u; float f; } v; v.u = ((unsigned)(unsigned short)s) << 16;
  return v.f;
}

__device__ __forceinline__ void gll16(const void* g, void* l) {
  __builtin_amdgcn_global_load_lds(
      (const __attribute__((address_space(1))) unsigned int*)g,
      (__attribute__((address_space(3))) unsigned int*)l, 16, 0, 0);
}

__device__ __forceinline__ float wsum(float v) {
#pragma unroll
  for (int off = 32; off > 0; off >>= 1) v += __shfl_xor(v, off, 64);
  return v;
}

// ---------------- 4-way weight split fp32 -> hi/lo bf16 ----------------
__global__ void splitw4(const float* __restrict__ w0, const float* __restrict__ w1,
                        const float* __restrict__ w2, const float* __restrict__ w3,
                        short* h0, short* l0_, short* h1, short* l1_,
                        short* h2_, short* l2_, short* h3_, short* l3_) {
  const int z = blockIdx.z;
  const float* in = (z == 0) ? w0 : (z == 1) ? w1 : (z == 2) ? w2 : w3;
  short* hi = (z == 0) ? h0 : (z == 1) ? h1 : (z == 2) ? h2_ : h3_;
  short* lo = (z == 0) ? l0_ : (z == 1) ? l1_ : (z == 2) ? l2_ : l3_;
  int i = (blockIdx.x * 256 + threadIdx.x) * 4;
  if (i >= DD * DD) return;
  float4 v = *(const float4*)(in + i);
  short4 h4, l4;
  h4.x = f2b(v.x); l4.x = f2b(v.x - b2f(h4.x));
  h4.y = f2b(v.y); l4.y = f2b(v.y - b2f(h4.y));
  h4.z = f2b(v.z); l4.z = f2b(v.z - b2f(h4.z));
  h4.w = f2b(v.w); l4.w = f2b(v.w - b2f(h4.w));
  *(short4*)(hi + i) = h4;
  *(short4*)(lo + i) = l4;
}

// ---------------- tril(lat) -> split bf16 hi/lo ----------------
__global__ void splitlat(const float* __restrict__ lat, short* __restrict__ hi,
                         short* __restrict__ lo) {
  int i = (blockIdx.x * 256 + threadIdx.x) * 4;
  int r = i >> 11;
  int c = i & 2047;
  float4 v = *(const float4*)(lat + i);
  if (c + 0 > r) v.x = 0.0f;
  if (c + 1 > r) v.y = 0.0f;
  if (c + 2 > r) v.z = 0.0f;
  if (c + 3 > r) v.w = 0.0f;
  short4 h4, l4;
  h4.x = f2b(v.x); l4.x = f2b(v.x - b2f(h4.x));
  h4.y = f2b(v.y); l4.y = f2b(v.y - b2f(h4.y));
  h4.z = f2b(v.z); l4.z = f2b(v.z - b2f(h4.z));
  h4.w = f2b(v.w); l4.w = f2b(v.w - b2f(h4.w));
  *(short4*)(hi + i) = h4;
  *(short4*)(lo + i) = l4;
}

// ---------------- fp32 -> bf16 single ----------------
__global__ void cvtb(const float* __restrict__ in, short* __restrict__ out, int n) {
  int i = (blockIdx.x * 256 + threadIdx.x) * 4;
  if (i >= n) return;
  float4 v = *(const float4*)(in + i);
  short4 o; o.x = f2b(v.x); o.y = f2b(v.y); o.z = f2b(v.z); o.w = f2b(v.w);
  *(short4*)(out + i) = o;
}

// ---------------- elementwise sum (in-place capable): o = a + b ----------------
__global__ void sum2(const float* __restrict__ a, const float* __restrict__ bq,
                     float* __restrict__ o) {
  int i = (blockIdx.x * 256 + threadIdx.x) * 4;
  float4 va = *(const float4*)(a + i);
  float4 vb = *(const float4*)(bq + i);
  float4 vo = {va.x + vb.x, va.y + vb.y, va.z + vb.z, va.w + vb.w};
  *(float4*)(o + i) = vo;
}

// ---------------- transpose + convert: in f32 [R][C] -> out bf16 [C][R] ----------------
__global__ void transp_cvt(const float* __restrict__ in, short* __restrict__ out,
                           int R, int C) {
  __shared__ float t[32][33];
  int c0 = blockIdx.x * 32, r0 = blockIdx.y * 32;
#pragma unroll
  for (int i = 0; i < 4; i++) {
    int idx = threadIdx.x + i * 256;
    int r = idx >> 5, c = idx & 31;
    t[r][c] = in[(size_t)(r0 + r) * C + c0 + c];
  }
  __syncthreads();
#pragma unroll
  for (int i = 0; i < 4; i++) {
    int idx = threadIdx.x + i * 256;
    int cc = idx >> 5, rr = idx & 31;
    out[(size_t)(c0 + cc) * R + r0 + rr] = f2b(t[rr][cc]);
  }
}

// ---------------- rmsnorm fp32 -> split bf16 ----------------
__global__ void rmsnorm_hl(const float* __restrict__ x, const float* __restrict__ w,
                           short* __restrict__ oh, short* __restrict__ ol, int rows) {
  int wid = blockIdx.x * 4 + (threadIdx.x >> 6);
  int lane = threadIdx.x & 63;
  if (wid >= rows) return;
  const float* xp = x + (size_t)wid * DD + lane * 8;
  float4 a = *(const float4*)xp;
  float4 b = *(const float4*)(xp + 4);
  float ss = a.x*a.x + a.y*a.y + a.z*a.z + a.w*a.w
           + b.x*b.x + b.y*b.y + b.z*b.z + b.w*b.w;
  ss = wsum(ss);
  float r = rsqrtf(ss * (1.0f / DD) + 1e-6f);
  const float* wp = w + lane * 8;
  float4 wa = *(const float4*)wp, wb = *(const float4*)(wp + 4);
  float o8[8] = {a.x*r*wa.x, a.y*r*wa.y, a.z*r*wa.z, a.w*r*wa.w,
                 b.x*r*wb.x, b.y*r*wb.y, b.z*r*wb.z, b.w*r*wb.w};
  short hv[8], lv[8];
#pragma unroll
  for (int i = 0; i < 8; i++) { hv[i] = f2b(o8[i]); lv[i] = f2b(o8[i] - b2f(hv[i])); }
  short* op = oh + (size_t)wid * DD + lane * 8;
  short* lp = ol + (size_t)wid * DD + lane * 8;
  *(short4*)op = make_short4(hv[0], hv[1], hv[2], hv[3]);
  *(short4*)(op + 4) = make_short4(hv[4], hv[5], hv[6], hv[7]);
  *(short4*)lp = make_short4(lv[0], lv[1], lv[2], lv[3]);
  *(short4*)(lp + 4) = make_short4(lv[4], lv[5], lv[6], lv[7]);
}

// ======================= unified bf16 GEMM, gll16 staging =======================
template <bool SPL, int OM, bool ROPE>
__global__ __launch_bounds__(256) void ggemm(const short* __restrict__ Ah_g,
                                             const short* __restrict__ Al_g,
                                             const short* __restrict__ Bh_g,
                                             const short* __restrict__ Bl_g,
                                             const float* __restrict__ ADD,
                                             void* __restrict__ C, void* __restrict__ C2,
                                             int M, int N, int K) {
  __shared__ short Ahs[128 * 32];
  __shared__ short Bhs[128 * 32];
  __shared__ short Als[SPL ? 128 * 32 : 8];
  __shared__ short Bls[SPL ? 128 * 32 : 8];
  const int tid = threadIdx.x, l = tid & 63, w = tid >> 6;
  const int wr = (w >> 1) * 64, wc = (w & 1) * 64;
  const int bm = blockIdx.y * 128, bn = blockIdx.x * 128;
  f32x4 acc[4][4] = {};
  for (int k0 = 0; k0 < K; k0 += 32) {
#pragma unroll
    for (int p = 0; p < 2; p++) {
      int row = p * 64 + (tid >> 2), g = tid & 3;
      int swz = (g ^ ((row >> 1) & 3)) * 8;
      gll16(Ah_g + (size_t)(bm + row) * K + k0 + swz, Ahs + p * 2048 + tid * 8);
      gll16(Bh_g + (size_t)(bn + row) * K + k0 + swz, Bhs + p * 2048 + tid * 8);
      if (SPL) {
        gll16(Al_g + (size_t)(bm + row) * K + k0 + swz, Als + p * 2048 + tid * 8);
        gll16(Bl_g + (size_t)(bn + row) * K + k0 + swz, Bls + p * 2048 + tid * 8);
      }
    }
    __syncthreads();
    bf16x8 ah[4], bh[4], al[4], bl[4];
#pragma unroll
    for (int m = 0; m < 4; m++) {
      int r = wr + m * 16 + (l & 15);
      int go = (((l >> 4) ^ ((r >> 1) & 3)) << 3);
      ah[m] = *(const bf16x8*)(Ahs + r * 32 + go);
      if (SPL) al[m] = *(const bf16x8*)(Als + r * 32 + go);
    }
#pragma unroll
    for (int n = 0; n < 4; n++) {
      int r = wc + n * 16 + (l & 15);
      int go = (((l >> 4) ^ ((r >> 1) & 3)) << 3);
      bh[n] = *(const bf16x8*)(Bhs + r * 32 + go);
      if (SPL) bl[n] = *(const bf16x8*)(Bls + r * 32 + go);
    }
#pragma unroll
    for (int m = 0; m < 4; m++)
#pragma unroll
      for (int n = 0; n < 4; n++) {
        acc[m][n] = __builtin_amdgcn_mfma_f32_16x16x32_bf16(ah[m], bh[n], acc[m][n], 0, 0, 0);
        if (SPL) {
          acc[m][n] = __builtin_amdgcn_mfma_f32_16x16x32_bf16(ah[m], bl[n], acc[m][n], 0, 0, 0);
          acc[m][n] = __builtin_amdgcn_mfma_f32_16x16x32_bf16(al[m], bh[n], acc[m][n], 0, 0, 0);
        }
      }
    __syncthreads();
  }
  const int ll = l & 15, lg4 = (l >> 4) * 4;
  if (ROPE) {
#pragma unroll
    for (int m = 0; m < 4; m++)
#pragma unroll
      for (int n = 0; n < 2; n++) {
        int i_ = n * 16 + ll;
        float inv = exp2f(-(float)i_ * (13.287712379549449f / 32.0f));
#pragma unroll
        for (int j = 0; j < 4; j++) {
          int gm = bm + wr + m * 16 + lg4 + j;
          int s = gm & (SS - 1);
          float ang = (float)s * inv;
          float sn, cs;
          sincosf(ang, &sn, &cs);
          float v1 = acc[m][n][j], v2 = acc[m][n + 2][j];
          acc[m][n][j]     = v1 * cs - v2 * sn;
          acc[m][n + 2][j] = v2 * cs + v1 * sn;
        }
      }
  }
#pragma unroll
  for (int m = 0; m < 4; m++)
#pragma unroll
    for (int n = 0; n < 4; n++) {
      int gn = bn + wc + n * 16 + ll;
#pragma unroll
      for (int j = 0; j < 4; j++) {
        int gm = bm + wr + m * 16 + lg4 + j;
        if (gm >= M || gn >= N) continue;
        float v = acc[m][n][j];
        if (OM == 0) {
          ((float*)C)[(size_t)gm * N + gn] = v;
        } else if (OM == 1) {
          ((short*)C)[(size_t)gm * N + gn] = f2b(v);
        } else if (OM == 6) {
          size_t off = (size_t)gm * N + gn;
          ((float*)C)[off] = v + ADD[off];
        } else {
          short hi = f2b(v);
          short lo = f2b(v - b2f(hi));
          int b = gm >> 11, s = gm & (SS - 1);
          int hh2 = gn >> 6, d = gn & 63;
          size_t off;
          if (OM == 2)      off = (((size_t)(b * HH + hh2)) * SS + s) * 64 + d;
          else if (OM == 3) off = (((size_t)(b * HH + hh2)) * 64 + d) * SS + s;
          else              off = ((size_t)(b * DD) + gn) * SS + s;
          ((short*)C)[off] = hi;
          ((short*)C2)[off] = lo;
        }
      }
    }
}

// ======================= fused QKV GEMM: z selects weight/output =======================
__global__ __launch_bounds__(256) void qkv_g(const short* __restrict__ Ah_g,
                                             const short* __restrict__ Al_g,
                                             const short* __restrict__ wh0, const short* __restrict__ wl0,
                                             const short* __restrict__ wh1, const short* __restrict__ wl1,
                                             const short* __restrict__ wh2, const short* __restrict__ wl2,
                                             short* __restrict__ c0h, short* __restrict__ c0l,
                                             short* __restrict__ c1h, short* __restrict__ c1l,
                                             short* __restrict__ c2h, short* __restrict__ c2l) {
  const int z = blockIdx.z;
  const short* Bh_g = (z == 0) ? wh0 : (z == 1) ? wh1 : wh2;
  const short* Bl_g = (z == 0) ? wl0 : (z == 1) ? wl1 : wl2;
  short* Ch = (z == 0) ? c0h : (z == 1) ? c1h : c2h;
  short* Cl = (z == 0) ? c0l : (z == 1) ? c1l : c2l;
  const int K = DD;
  __shared__ short Ahs[128 * 32];
  __shared__ short Bhs[128 * 32];
  __shared__ short Als[128 * 32];
  __shared__ short Bls[128 * 32];
  const int tid = threadIdx.x, l = tid & 63, w = tid >> 6;
  const int wr = (w >> 1) * 64, wc = (w & 1) * 64;
  const int bm = blockIdx.y * 128, bn = blockIdx.x * 128;
  f32x4 acc[4][4] = {};
  for (int k0 = 0; k0 < K; k0 += 32) {
#pragma unroll
    for (int p = 0; p < 2; p++) {
      int row = p * 64 + (tid >> 2), g = tid & 3;
      int swz = (g ^ ((row >> 1) & 3)) * 8;
      gll16(Ah_g + (size_t)(bm + row) * K + k0 + swz, Ahs + p * 2048 + tid * 8);
      gll16(Bh_g + (size_t)(bn + row) * K + k0 + swz, Bhs + p * 2048 + tid * 8);
      gll16(Al_g + (size_t)(bm + row) * K + k0 + swz, Als + p * 2048 + tid * 8);
      gll16(Bl_g + (size_t)(bn + row) * K + k0 + swz, Bls + p * 2048 + tid * 8);
    }
    __syncthreads();
    bf16x8 ah[4], bh[4], al[4], bl[4];
#pragma unroll
    for (int m = 0; m < 4; m++) {
      int r = wr + m * 16 + (l & 15);
      int go = (((l >> 4) ^ ((r >> 1) & 3)) << 3);
      ah[m] = *(const bf16x8*)(Ahs + r * 32 + go);
      al[m] = *(const bf16x8*)(Als + r * 32 + go);
    }
#pragma unroll
    for (int n = 0; n < 4; n++) {
      int r = wc + n * 16 + (l & 15);
      int go = (((l >> 4) ^ ((r >> 1) & 3)) << 3);
      bh[n] = *(const bf16x8*)(Bhs + r * 32 + go);
      bl[n] = *(const bf16x8*)(Bls + r * 32 + go);
    }
#pragma unroll
    for (int m = 0; m < 4; m++)
#pragma unroll
      for (int n = 0; n < 4; n++) {
        acc[m][n] = __builtin_amdgcn_mfma_f32_16x16x32_bf16(ah[m], bh[n], acc[m][n], 0, 0, 0);
        acc[m][n] = __builtin_amdgcn_mfma_f32_16x16x32_bf16(ah[m], bl[n], acc[m][n], 0, 0, 0);
        acc[m][n] = __builtin_amdgcn_mfma_f32_16x16x32_bf16(al[m], bh[n], acc[m][n], 0, 0, 0);
      }
    __syncthreads();
  }
  const int ll = l & 15, lg4 = (l >> 4) * 4;
  if (z < 2) {  // RoPE on q, k
#pragma unroll
    for (int m = 0; m < 4; m++)
#pragma unroll
      for (int n = 0; n < 2; n++) {
        int i_ = n * 16 + ll;
        float inv = exp2f(-(float)i_ * (13.287712379549449f / 32.0f));
#pragma unroll
        for (int j = 0; j < 4; j++) {
          int gm = bm + wr + m * 16 + lg4 + j;
          int s = gm & (SS - 1);
          float ang = (float)s * inv;
          float sn, cs;
          sincosf(ang, &sn, &cs);
          float v1 = acc[m][n][j], v2 = acc[m][n + 2][j];
          acc[m][n][j]     = v1 * cs - v2 * sn;
          acc[m][n + 2][j] = v2 * cs + v1 * sn;
        }
      }
  }
#pragma unroll
  for (int m = 0; m < 4; m++)
#pragma unroll
    for (int n = 0; n < 4; n++) {
      int gn = bn + wc + n * 16 + ll;
#pragma unroll
      for (int j = 0; j < 4; j++) {
        int gm = bm + wr + m * 16 + lg4 + j;
        float v = acc[m][n][j];
        short hi = f2b(v);
        short lo = f2b(v - b2f(hi));
        int b = gm >> 11, s = gm & (SS - 1);
        int hh2 = gn >> 6, d = gn & 63;
        size_t off = (z < 2) ? ((((size_t)(b * HH + hh2)) * SS + s) * 64 + d)
                             : ((((size_t)(b * HH + hh2)) * 64 + d) * SS + s);
        Ch[off] = hi;
        Cl[off] = lo;
      }
    }
}

// ======================= lateral GEMM: pre-split A, split-K=2, rotated output =======================
__global__ __launch_bounds__(256) void lat_g(const short* __restrict__ lath,
                                             const short* __restrict__ latl,
                                             const short* __restrict__ bTh,
                                             const short* __restrict__ bTl,
                                             float* __restrict__ P0,
                                             float* __restrict__ P1) {
  const int zb = blockIdx.z >> 1;
  const int half = blockIdx.z & 1;
  bTh += (size_t)zb * DD * SS;
  bTl += (size_t)zb * DD * SS;
  float* Cc = (half == 0 ? P0 : P1) + (size_t)zb * DD * SS;
  __shared__ short Ah[128 * 32];
  __shared__ short Al[128 * 32];
  __shared__ short Bh[128 * 32];
  __shared__ short Bl[128 * 32];
  const int tid = threadIdx.x, l = tid & 63, w = tid >> 6;
  const int wr = (w >> 1) * 64, wc = (w & 1) * 64;
  const int bm = blockIdx.y * 128, bn = blockIdx.x * 128;
  const int T = blockIdx.y + 1;
  const int h0 = (T + 1) >> 1;
  const int kbeg = (half == 0) ? 0 : h0 * 128;
  const int kend = (half == 0) ? h0 * 128 : T * 128;
  f32x4 acc[4][4] = {};
  const int ll = l & 15, lg4 = (l >> 4) * 4;
  for (int k0 = kbeg; k0 < kend; k0 += 32) {
#pragma unroll
    for (int p = 0; p < 2; p++) {
      int row = p * 64 + (tid >> 2), g = tid & 3;
      int swz = (g ^ ((row >> 1) & 3)) * 8;
      gll16(bTh + (size_t)(bn + row) * SS + k0 + swz, Bh + p * 2048 + tid * 8);
      gll16(bTl + (size_t)(bn + row) * SS + k0 + swz, Bl + p * 2048 + tid * 8);
      gll16(lath + (size_t)(bm + row) * SS + k0 + swz, Ah + p * 2048 + tid * 8);
      gll16(latl + (size_t)(bm + row) * SS + k0 + swz, Al + p * 2048 + tid * 8);
    }
    __syncthreads();
    bf16x8 ah[4], bh[4], al[4], bl[4];
#pragma unroll
    for (int m = 0; m < 4; m++) {
      int r = wr + m * 16 + (l & 15);
      int go = (((l >> 4) ^ ((r >> 1) & 3)) << 3);
      ah[m] = *(const bf16x8*)(Ah + r * 32 + go);
      al[m] = *(const bf16x8*)(Al + r * 32 + go);
    }
#pragma unroll
    for (int n = 0; n < 4; n++) {
      int r = wc + n * 16 + (l & 15);
      int go = (((l >> 4) ^ ((r >> 1) & 3)) << 3);
      bh[n] = *(const bf16x8*)(Bh + r * 32 + go);
      bl[n] = *(const bf16x8*)(Bl + r * 32 + go);
    }
#pragma unroll
    for (int m = 0; m < 4; m++)
#pragma unroll
      for (int n = 0; n < 4; n++) {
        acc[m][n] = __builtin_amdgcn_mfma_f32_16x16x32_bf16(ah[m], bh[n], acc[m][n], 0, 0, 0);
        acc[m][n] = __builtin_amdgcn_mfma_f32_16x16x32_bf16(ah[m], bl[n], acc[m][n], 0, 0, 0);
        acc[m][n] = __builtin_amdgcn_mfma_f32_16x16x32_bf16(al[m], bh[n], acc[m][n], 0, 0, 0);
      }
    __syncthreads();
  }
#pragma unroll
  for (int m = 0; m < 4; m++)
#pragma unroll
    for (int n = 0; n < 4; n++) {
      int gn = bn + wc + n * 16 + ll;
#pragma unroll
      for (int j = 0; j < 4; j++) {
        int gm = bm + wr + m * 16 + lg4 + j;
        size_t off = ((size_t)((gm >> 5) * 512 + gn)) * 32 + ((gm + gn) & 31);
        Cc[off] = acc[m][n][j];
      }
    }
}

// ======================= flash attention (P hi-only PV) =======================
__global__ __launch_bounds__(256) void attn_g(const short* __restrict__ qh,
                                              const short* __restrict__ ql,
                                              const short* __restrict__ kh,
                                              const short* __restrict__ kl,
                                              const short* __restrict__ vh,
                                              const short* __restrict__ vl,
                                              short* __restrict__ aho,
                                              short* __restrict__ alo) {
  const int h = blockIdx.y, b = blockIdx.z;
  const int qt = (b == 0) ? (int)blockIdx.x : 31 - (int)blockIdx.x;
  const int q0 = qt * 64;
  const int tid = threadIdx.x, w = tid >> 6, l = tid & 63;
  const int lg = l >> 4, ll = l & 15;
  __shared__ short Kh[64 * 64], Kl[64 * 64];
  __shared__ short Vh[64 * 64], Vl[64 * 64];
  __shared__ short Ph[64 * 64];
  const size_t bh = (size_t)(b * HH + h);

  const int qr = q0 + w * 16 + ll;
  const short* qbh = qh + (bh * SS + qr) * 64;
  const short* qbl = ql + (bh * SS + qr) * 64;
  bf16x8 qfh[2], qfl[2];
#pragma unroll
  for (int ks = 0; ks < 2; ks++) {
    qfh[ks] = *(const bf16x8*)(qbh + (ks * 4 + lg) * 8);
    qfl[ks] = *(const bf16x8*)(qbl + (ks * 4 + lg) * 8);
  }

  f32x4 o[4] = {};
  float mrow[4] = {-1e30f, -1e30f, -1e30f, -1e30f};
  float lsum[4] = {};
  const int qrow0 = q0 + w * 16 + lg * 4;
  const int ntiles = qt + 1;

  for (int kt = 0; kt < ntiles; kt++) {
#pragma unroll
    for (int p = 0; p < 2; p++) {
      int row = p * 32 + (tid >> 3), g = tid & 7;
      int sw = ((g ^ (row & 7)) << 3);
      size_t krow = (bh * SS + kt * 64 + row) * 64;
      size_t vrow = (bh * 64 + row) * SS + kt * 64;
      gll16(kh + krow + sw, Kh + p * 2048 + tid * 8);
      gll16(kl + krow + sw, Kl + p * 2048 + tid * 8);
      gll16(vh + vrow + sw, Vh + p * 2048 + tid * 8);
      gll16(vl + vrow + sw, Vl + p * 2048 + tid * 8);
    }
    __syncthreads();

    f32x4 sv[4] = {};
#pragma unroll
    for (int nf = 0; nf < 4; nf++) {
      int r = nf * 16 + ll;
#pragma unroll
      for (int ks = 0; ks < 2; ks++) {
        int g = (ks * 4 + lg) ^ (r & 7);
        bf16x8 khf = *(const bf16x8*)(Kh + r * 64 + g * 8);
        bf16x8 klf = *(const bf16x8*)(Kl + r * 64 + g * 8);
        sv[nf] = __builtin_amdgcn_mfma_f32_16x16x32_bf16(qfh[ks], khf, sv[nf], 0, 0, 0);
        sv[nf] = __builtin_amdgcn_mfma_f32_16x16x32_bf16(qfh[ks], klf, sv[nf], 0, 0, 0);
        sv[nf] = __builtin_amdgcn_mfma_f32_16x16x32_bf16(qfl[ks], khf, sv[nf], 0, 0, 0);
      }
    }
#pragma unroll
    for (int nf = 0; nf < 4; nf++) {
      int kpos = kt * 64 + nf * 16 + ll;
#pragma unroll
      for (int j = 0; j < 4; j++) {
        float v = sv[nf][j] * 0.125f;
        sv[nf][j] = (kpos > qrow0 + j) ? -1e30f : v;
      }
    }
    float cf[4];
#pragma unroll
    for (int j = 0; j < 4; j++) {
      float r = fmaxf(fmaxf(sv[0][j], sv[1][j]), fmaxf(sv[2][j], sv[3][j]));
      r = fmaxf(r, __shfl_xor(r, 1)); r = fmaxf(r, __shfl_xor(r, 2));
      r = fmaxf(r, __shfl_xor(r, 4)); r = fmaxf(r, __shfl_xor(r, 8));
      float mn = fmaxf(mrow[j], r);
      cf[j] = __expf(mrow[j] - mn);
      mrow[j] = mn;
    }
    float ps[4] = {};
#pragma unroll
    for (int nf = 0; nf < 4; nf++)
#pragma unroll
      for (int j = 0; j < 4; j++) {
        float p = __expf(sv[nf][j] - mrow[j]);
        sv[nf][j] = p;
        ps[j] += p;
      }
#pragma unroll
    for (int j = 0; j < 4; j++) {
      float r = ps[j];
      r += __shfl_xor(r, 1); r += __shfl_xor(r, 2);
      r += __shfl_xor(r, 4); r += __shfl_xor(r, 8);
      lsum[j] = lsum[j] * cf[j] + r;
    }
#pragma unroll
    for (int nf = 0; nf < 4; nf++)
#pragma unroll
      for (int j = 0; j < 4; j++) o[nf][j] *= cf[j];
    // write P (hi only)
#pragma unroll
    for (int nf = 0; nf < 4; nf++)
#pragma unroll
      for (int j = 0; j < 4; j++) {
        int rowP = w * 16 + lg * 4 + j;
        int col = nf * 16 + ll;
        int off = rowP * 64 + (((col >> 3) ^ (rowP & 7)) << 3) + (col & 7);
        Ph[off] = f2b(sv[nf][j]);
      }
    __syncthreads();
    bf16x8 pfh[2];
    {
      int rowA = w * 16 + ll;
#pragma unroll
      for (int ks = 0; ks < 2; ks++) {
        int g = (ks * 4 + lg) ^ (rowA & 7);
        pfh[ks] = *(const bf16x8*)(Ph + rowA * 64 + g * 8);
      }
    }
#pragma unroll
    for (int nf = 0; nf < 4; nf++) {
      int r = nf * 16 + ll;
#pragma unroll
      for (int ks = 0; ks < 2; ks++) {
        int g = (ks * 4 + lg) ^ (r & 7);
        bf16x8 vhf = *(const bf16x8*)(Vh + r * 64 + g * 8);
        bf16x8 vlf = *(const bf16x8*)(Vl + r * 64 + g * 8);
        o[nf] = __builtin_amdgcn_mfma_f32_16x16x32_bf16(pfh[ks], vhf, o[nf], 0, 0, 0);
        o[nf] = __builtin_amdgcn_mfma_f32_16x16x32_bf16(pfh[ks], vlf, o[nf], 0, 0, 0);
      }
    }
    __syncthreads();
  }
  float inv[4];
#pragma unroll
  for (int j = 0; j < 4; j++) inv[j] = 1.0f / lsum[j];
#pragma unroll
  for (int nf = 0; nf < 4; nf++)
#pragma unroll
    for (int j = 0; j < 4; j++) {
      float v = o[nf][j] * inv[j];
      short hi = f2b(v);
      size_t off = ((size_t)(b * SS + qrow0 + j)) * DD + h * HDD + nf * 16 + ll;
      aho[off] = hi;
      alo[off] = f2b(v - b2f(hi));
    }
}

// ======================= ALIF scan: single-stream async-LDS (latency-floor bound) =======================
#define ACH 32
__global__ __launch_bounds__(64) void tsa_alif8(const float* __restrict__ mixedS,
                                                const float* __restrict__ bt,
                                                const float* __restrict__ asw,
                                                float* __restrict__ spikesS) {
  __shared__ float lds[2][ACH * 64];  // 16 KB
  const int t = threadIdx.x;
  const int tid = blockIdx.x * 64 + t;
  const int b = tid >> 9, d = tid & 511;
  const int d0 = d & ~63;
  const float btd = bt[d], asd = asw[d];
  const float C = 36.06737602222409f;  // 25 * log2(e)
  const float bt36 = btd * C, as36 = asd * C;
  const float bt99 = 0.99f * btd, as99 = 0.99f * asd;
  const size_t bbase = (size_t)b * DD * SS;
  const float* mp = mixedS + bbase;
  float* sp = spikesS + bbase;
  {
    const float* g0 = mp + (size_t)d0 * 32;
#pragma unroll
    for (int i = 0; i < 8; i++) gll16(g0 + i * 256 + t * 4, &lds[0][i * 256 + t * 4]);
  }
  float vR = 0.0f, ad = 0.0f;
  for (int c = 0; c < SS / ACH; c++) {
    const int cur = c & 1;
    __syncthreads();
    if (c + 1 < SS / ACH) {
      const float* gq = mp + ((size_t)((c + 1) * 512 + d0)) * 32;
#pragma unroll
      for (int i = 0; i < 8; i++) gll16(gq + i * 256 + t * 4, &lds[cur ^ 1][i * 256 + t * 4]);
    }
    float m[ACH];
#pragma unroll
    for (int j = 0; j < ACH; j++) m[j] = lds[cur][t * 32 + ((j + t) & 31)];
    vR += m[0];
    float sO[ACH];
#pragma unroll
    for (int j = 0; j < ACH; j++) {
      float thC = fmaf(ad, as36, bt36);
      float th99 = fmaf(ad, as99, bt99);
      float arg = fmaf(vR, -C, thC);
      float e = exp2f(arg);
      float s = __builtin_amdgcn_rcpf(1.0f + e);
      sO[j] = s;
      float pre = (j + 1 < ACH) ? fmaf(0.99f, vR, m[j + 1]) : (0.99f * vR);
      vR = fmaf(-th99, s, pre);
      ad = fmaf(0.95f, ad, s);
    }
#pragma unroll
    for (int j = 0; j < ACH; j++) lds[cur][t * 32 + ((j + t) & 31)] = sO[j];
    __syncthreads();
    float* so = sp + ((size_t)(c * 512 + d0)) * 32;
#pragma unroll
    for (int i = 0; i < 8; i++) {
      float4 v4 = *(const float4*)&lds[cur][i * 256 + t * 4];
      *(float4*)(so + i * 256 + t * 4) = v4;
    }
  }
}

// ======================= h2 = x + mixedS^T + spikes^T (rotated layouts) =======================
__global__ __launch_bounds__(256) void fuse_h2(const float* __restrict__ x,
                                               const float* __restrict__ mixedS,
                                               const float* __restrict__ spikesS,
                                               float* __restrict__ h2) {
  const int s0 = blockIdx.x * 64, d0 = blockIdx.y * 64, b = blockIdx.z;
  __shared__ float t[64][65];
  const int dl = threadIdx.x >> 2;
  const int grp = threadIdx.x & 3;
  const size_t bbase = (size_t)b * DD * SS;
#pragma unroll
  for (int i = 0; i < 16; i++) {
    int sl = grp * 16 + i;
    int sg = s0 + sl;
    size_t off = bbase + ((size_t)((sg >> 5) * 512 + d0 + dl)) * 32 + ((sg + dl) & 31);
    t[dl][sl] = mixedS[off] + spikesS[off];
  }
  __syncthreads();
#pragma unroll
  for (int k = 0; k < 4; k++) {
    int sl = threadIdx.x >> 2;
    int dl2 = (threadIdx.x & 3) * 16 + k * 4;
    size_t off = ((size_t)(b * SS + s0 + sl)) * DD + d0 + dl2;
    float4 xv = *(const float4*)(x + off);
    float4 o;
    o.x = xv.x + t[dl2 + 0][sl];
    o.y = xv.y + t[dl2 + 1][sl];
    o.z = xv.z + t[dl2 + 2][sl];
    o.w = xv.w + t[dl2 + 3][sl];
    *(float4*)(h2 + off) = o;
  }
}

// ======================= tree kernels =======================
__global__ void tree_reduce_b(const float* __restrict__ sin_, const float* __restrict__ tn1,
                              short* __restrict__ nb, int Sn) {
  int wid = blockIdx.x * 4 + (threadIdx.x >> 6);
  int lane = threadIdx.x & 63;
  int rows = BB * Sn;
  if (wid >= rows) return;
  int b = wid / Sn, j = wid - b * Sn;
  const float* r0 = sin_ + ((size_t)(b * 2 * Sn + 2 * j)) * DD + lane * 8;
  const float* r1 = r0 + DD;
  float4 a0 = *(const float4*)r0, a1 = *(const float4*)(r0 + 4);
  float4 b0 = *(const float4*)r1, b1 = *(const float4*)(r1 + 4);
  float ra[8] = {a0.x + b0.x, a0.y + b0.y, a0.z + b0.z, a0.w + b0.w,
                 a1.x + b1.x, a1.y + b1.y, a1.z + b1.z, a1.w + b1.w};
  float ss = 0.0f;
#pragma unroll
  for (int i = 0; i < 8; i++) ss += ra[i] * ra[i];
  ss = wsum(ss);
  float rms = rsqrtf(ss * (1.0f / DD) + 1e-6f);
  const float* wp = tn1 + lane * 8;
  float4 wa = *(const float4*)wp, wb = *(const float4*)(wp + 4);
  float wv8[8] = {wa.x, wa.y, wa.z, wa.w, wb.x, wb.y, wb.z, wb.w};
  short* np = nb + (size_t)wid * DD + lane * 8;
  short4 n0, n1;
  n0.x = f2b(ra[0]*rms*wv8[0]); n0.y = f2b(ra[1]*rms*wv8[1]);
  n0.z = f2b(ra[2]*rms*wv8[2]); n0.w = f2b(ra[3]*rms*wv8[3]);
  n1.x = f2b(ra[4]*rms*wv8[4]); n1.y = f2b(ra[5]*rms*wv8[5]);
  n1.z = f2b(ra[6]*rms*wv8[6]); n1.w = f2b(ra[7]*rms*wv8[7]);
  *(short4*)np = n0;
  *(short4*)(np + 4) = n1;
}

// fused: combine(lvl) + reduce(lvl+1). Block = 4 combine rows -> 2 reduce rows.
// Next-level reduce row wid2 reads exactly global sout rows 2*wid2, 2*wid2+1
// (b*Sn + 2j == 2*(b*Sn/2 + j)), so the exchange is intra-block via LDS.
__global__ void tree_cr(const float* __restrict__ g, const short* __restrict__ nbin,
                        const float* __restrict__ sin_, const float* __restrict__ tn1,
                        const float* __restrict__ tn2, float* __restrict__ sout,
                        short* __restrict__ nbout, int Sn, int donext) {
  __shared__ float lds[4][512];
  const int w = threadIdx.x >> 6;
  const int lane = threadIdx.x & 63;
  const int wid = blockIdx.x * 4 + w;
  const int rows = BB * Sn;
  if (wid < rows) {
    int b = wid / Sn, j = wid - b * Sn;
    const float* r0 = sin_ + ((size_t)(b * 2 * Sn + 2 * j)) * DD + lane * 8;
    const float* r1 = r0 + DD;
    float4 a0 = *(const float4*)r0, a1 = *(const float4*)(r0 + 4);
    float4 b0 = *(const float4*)r1, b1 = *(const float4*)(r1 + 4);
    float res[8] = {0.5f*(a0.x + b0.x), 0.5f*(a0.y + b0.y), 0.5f*(a0.z + b0.z), 0.5f*(a0.w + b0.w),
                    0.5f*(a1.x + b1.x), 0.5f*(a1.y + b1.y), 0.5f*(a1.z + b1.z), 0.5f*(a1.w + b1.w)};
    size_t base = (size_t)wid * DD + lane * 8;
    float t[8];
    float ss = 0.0f;
#pragma unroll
    for (int i = 0; i < 8; i++) {
      float gg = 1.0f / (1.0f + expf(-g[base + i]));
      float tv = gg * b2f(nbin[base + i]) + (1.0f - gg) * res[i];
      t[i] = tv;
      ss += tv * tv;
    }
    ss = wsum(ss);
    float rms = rsqrtf(ss * (1.0f / DD) + 1e-6f);
#pragma unroll
    for (int i = 0; i < 8; i++) {
      float ov = t[i] * rms * tn2[lane * 8 + i];
      sout[base + i] = ov;
      lds[w][lane * 8 + i] = ov;
    }
  }
  __syncthreads();
  if (donext && w < 2) {
    int wid2 = blockIdx.x * 2 + w;
    int rows2 = rows >> 1;
    if (wid2 < rows2) {
      float ra[8];
      float ss = 0.0f;
#pragma unroll
      for (int i = 0; i < 8; i++) {
        ra[i] = lds[2 * w][lane * 8 + i] + lds[2 * w + 1][lane * 8 + i];
        ss += ra[i] * ra[i];
      }
      ss = wsum(ss);
      float rms = rsqrtf(ss * (1.0f / DD) + 1e-6f);
      const float* wp = tn1 + lane * 8;
      short* np = nbout + (size_t)wid2 * DD + lane * 8;
      short4 n0, n1;
      n0.x = f2b(ra[0]*rms*wp[0]); n0.y = f2b(ra[1]*rms*wp[1]);
      n0.z = f2b(ra[2]*rms*wp[2]); n0.w = f2b(ra[3]*rms*wp[3]);
      n1.x = f2b(ra[4]*rms*wp[4]); n1.y = f2b(ra[5]*rms*wp[5]);
      n1.z = f2b(ra[6]*rms*wp[6]); n1.w = f2b(ra[7]*rms*wp[7]);
      *(short4*)np = n0;
      *(short4*)(np + 4) = n1;
    }
  }
}

// h3 = h2 + root -> out fp32; hn = rmsnorm(h3) -> bf16
__global__ void h3hn_b(const float* __restrict__ h2, const float* __restrict__ root,
                       const float* __restrict__ fw, float* __restrict__ h3,
                       short* __restrict__ hn) {
  int wid = blockIdx.x * 4 + (threadIdx.x >> 6);
  int lane = threadIdx.x & 63;
  int b = wid >> 11;
  size_t base = (size_t)wid * DD + lane * 8;
  const float* rp = root + (size_t)b * DD + lane * 8;
  float t[8];
  float ss = 0.0f;
#pragma unroll
  for (int i = 0; i < 8; i++) {
    float tv = h2[base + i] + rp[i];
    t[i] = tv;
    ss += tv * tv;
    h3[base + i] = tv;
  }
  ss = wsum(ss);
  float rms = rsqrtf(ss * (1.0f / DD) + 1e-6f);
#pragma unroll
  for (int i = 0; i < 8; i++) hn[base + i] = f2b(t[i] * rms * fw[lane * 8 + i]);
}

// ======================= upgate =======================
__global__ __launch_bounds__(256) void upgate_g(const short* __restrict__ A,
                                                const short* __restrict__ Bv,
                                                short* __restrict__ ffa) {
  __shared__ short Ahs[128 * 32];
  __shared__ short B1s[128 * 32];
  __shared__ short B2s[128 * 32];
  const int tid = threadIdx.x, l = tid & 63, w = tid >> 6;
  const int wr = (w >> 1) * 64, wc = (w & 1) * 64;
  const int bm = blockIdx.y * 128, bn = blockIdx.x * 128;
  f32x4 acc1[4][4] = {}, acc2[4][4] = {};
  for (int k0 = 0; k0 < RANKK; k0 += 32) {
#pragma unroll
    for (int p = 0; p < 2; p++) {
      int row = p * 64 + (tid >> 2), g = tid & 3;
      int swz = (g ^ ((row >> 1) & 3)) * 8;
      gll16(A + (size_t)(bm + row) * RANKK + k0 + swz, Ahs + p * 2048 + tid * 8);
      gll16(Bv + (size_t)(bn + row) * RANKK + k0 + swz, B1s + p * 2048 + tid * 8);
      gll16(Bv + (size_t)(DFFF + bn + row) * RANKK + k0 + swz, B2s + p * 2048 + tid * 8);
    }
    __syncthreads();
    bf16x8 ah[4], b1[4], b2[4];
#pragma unroll
    for (int m = 0; m < 4; m++) {
      int r = wr + m * 16 + (l & 15);
      int go = (((l >> 4) ^ ((r >> 1) & 3)) << 3);
      ah[m] = *(const bf16x8*)(Ahs + r * 32 + go);
    }
#pragma unroll
    for (int n = 0; n < 4; n++) {
      int r = wc + n * 16 + (l & 15);
      int go = (((l >> 4) ^ ((r >> 1) & 3)) << 3);
      b1[n] = *(const bf16x8*)(B1s + r * 32 + go);
      b2[n] = *(const bf16x8*)(B2s + r * 32 + go);
    }
#pragma unroll
    for (int m = 0; m < 4; m++)
#pragma unroll
      for (int n = 0; n < 4; n++) {
        acc1[m][n] = __builtin_amdgcn_mfma_f32_16x16x32_bf16(ah[m], b1[n], acc1[m][n], 0, 0, 0);
        acc2[m][n] = __builtin_amdgcn_mfma_f32_16x16x32_bf16(ah[m], b2[n], acc2[m][n], 0, 0, 0);
      }
    __syncthreads();
  }
#pragma unroll
  for (int m = 0; m < 4; m++)
#pragma unroll
    for (int n = 0; n < 4; n++) {
      int gn = bn + wc + n * 16 + (l & 15);
#pragma unroll
      for (int j = 0; j < 4; j++) {
        int gm = bm + wr + m * 16 + (l >> 4) * 4 + j;
        float a = acc1[m][n][j];
        float s = a / (1.0f + __expf(-a));
        ffa[(size_t)gm * DFFF + gn] = f2b(s * acc2[m][n][j]);
      }
    }
}

// ======================= launch =======================
extern "C" void kernel_launch(void* const* d_in, const int* in_sizes, int n_in,
                              void* d_out, int out_size, void* d_ws, size_t ws_size,
                              hipStream_t stream) {
  const float* x   = (const float*)d_in[0];
  const float* nw  = (const float*)d_in[1];
  const float* wq  = (const float*)d_in[2];
  const float* wk  = (const float*)d_in[3];
  const float* wv  = (const float*)d_in[4];
  const float* wo  = (const float*)d_in[5];
  const float* lat = (const float*)d_in[6];
  const float* btp = (const float*)d_in[7];
  const float* asw = (const float*)d_in[8];
  const float* gw  = (const float*)d_in[9];
  const float* tn1 = (const float*)d_in[10];
  const float* tn2 = (const float*)d_in[11];
  const float* fnw = (const float*)d_in[12];
  const float* uw  = (const float*)d_in[13];
  const float* vw  = (const float*)d_in[14];
  const float* dw  = (const float*)d_in[15];
  float* out = (float*)d_out;
  char* W = (char*)d_ws;
  const size_t MB = 1u << 20;

  // layout (peak 40MB):
  // 0-8:   h / attn -> latP0(mixedS) -> nb0+gb+nb1
  // 8-16:  q / apT -> spikesS -> s0+s1
  // 16-24: k -> lath -> hn+t1
  // 24-32: v -> latl -> h2 -> ffa
  // 32-40: latP1 -> gwb/uwT/vwT/dwT
  short* h_hi = (short*)(W);
  short* h_lo = (short*)(W + 4 * MB);
  short* attn_hi = h_hi;
  short* attn_lo = h_lo;
  float* latP0 = (float*)(W);
  short* nb0 = (short*)(W);
  float* gb = (float*)(W + 2 * MB);
  short* nb1 = (short*)(W + 6 * MB);
  short* q_hi = (short*)(W + 8 * MB);
  short* q_lo = (short*)(W + 12 * MB);
  short* apT_hi = q_hi;
  short* apT_lo = q_lo;
  float* spikesS = (float*)(W + 8 * MB);
  float* s0 = (float*)(W + 8 * MB);
  float* s1 = (float*)(W + 12 * MB);
  short* k_hi = (short*)(W + 16 * MB);
  short* k_lo = (short*)(W + 20 * MB);
  short* lath = (short*)(W + 16 * MB);
  short* hn = (short*)(W + 16 * MB);
  short* t1 = (short*)(W + 20 * MB);
  short* v_hi = (short*)(W + 24 * MB);
  short* v_lo = (short*)(W + 28 * MB);
  short* latl = (short*)(W + 24 * MB);
  float* h2 = (float*)(W + 24 * MB);
  short* ffa = (short*)(W + 24 * MB);
  float* latP1 = (float*)(W + 32 * MB);
  short* gwb = (short*)(W + 32 * MB);
  short* uwT = gwb + 262144;
  short* vwT = uwT + 65536;
  short* dwT = vwT + 262144;

  short* wqh = (short*)out;
  short* wql = wqh + 262144;
  short* wkh = wql + 262144;
  short* wkl = wkh + 262144;
  short* wvh = wkl + 262144;
  short* wvl = wvh + 262144;
  short* woh = wvl + 262144;
  short* wol = woh + 262144;

  const int rows = BB * SS;  // 4096

  splitw4<<<dim3(256, 1, 4), 256, 0, stream>>>(wq, wk, wv, wo,
                                               wqh, wql, wkh, wkl, wvh, wvl, woh, wol);

  rmsnorm_hl<<<rows / 4, 256, 0, stream>>>(x, nw, h_hi, h_lo, rows);

  qkv_g<<<dim3(4, 32, 3), 256, 0, stream>>>(h_hi, h_lo,
                                            wqh, wql, wkh, wkl, wvh, wvl,
                                            q_hi, q_lo, k_hi, k_lo, v_hi, v_lo);

  attn_g<<<dim3(32, HH, BB), 256, 0, stream>>>(q_hi, q_lo, k_hi, k_lo, v_hi, v_lo,
                                               attn_hi, attn_lo);

  ggemm<true, 4, false><<<dim3(4, 32), 256, 0, stream>>>(
      attn_hi, attn_lo, woh, wol, nullptr, apT_hi, apT_lo, rows, DD, DD);

  splitlat<<<4096, 256, 0, stream>>>(lat, lath, latl);

  lat_g<<<dim3(4, 16, 4), 256, 0, stream>>>(lath, latl, apT_hi, apT_lo, latP0, latP1);

  // mixedS = latP0 + latP1 (layout-agnostic elementwise, in-place)
  sum2<<<(BB * DD * SS / 4) / 256, 256, 0, stream>>>(latP0, latP1, latP0);

  tsa_alif8<<<16, 64, 0, stream>>>(latP0, btp, asw, spikesS);
  fuse_h2<<<dim3(32, 8, 2), 256, 0, stream>>>(x, latP0, spikesS, h2);

  cvtb<<<256, 256, 0, stream>>>(gw, gwb, DD * DD);
  transp_cvt<<<dim3(4, 16), 256, 0, stream>>>(uw, uwT, DD, RANKK);
  transp_cvt<<<dim3(64, 4), 256, 0, stream>>>(vw, vwT, RANKK, 2 * DFFF);
  transp_cvt<<<dim3(16, 32), 256, 0, stream>>>(dw, dwT, DFFF, DD);

  // tree: 1 reduce + per level {gate GEMM, fused combine+next-reduce}
  const float* sin_ = h2;
  short* nbc = nb0;
  short* nbn = nb1;
  tree_reduce_b<<<(BB * 1024 + 3) / 4, 256, 0, stream>>>(sin_, tn1, nbc, 1024);
  for (int lvl = 0; lvl < 11; lvl++) {
    int Sn = 1024 >> lvl;
    int r2 = BB * Sn;
    float* sout = (lvl & 1) ? s1 : s0;
    ggemm<false, 0, false><<<dim3(4, (r2 + 127) / 128), 256, 0, stream>>>(
        nbc, nullptr, gwb, nullptr, nullptr, gb, nullptr, r2, DD, DD);
    tree_cr<<<(r2 + 3) / 4, 256, 0, stream>>>(gb, nbc, sin_, tn1, tn2, sout, nbn,
                                              Sn, lvl < 10 ? 1 : 0);
    sin_ = sout;
    short* tmp = nbc; nbc = nbn; nbn = tmp;
  }

  h3hn_b<<<rows / 4, 256, 0, stream>>>(h2, sin_, fnw, out, hn);

  ggemm<false, 1, false><<<dim3(1, 32), 256, 0, stream>>>(
      hn, nullptr, uwT, nullptr, nullptr, t1, nullptr, rows, RANKK, DD);
  upgate_g<<<dim3(8, 32), 256, 0, stream>>>(t1, vwT, ffa);
  ggemm<false, 6, false><<<dim3(4, 32), 256, 0, stream>>>(
      ffa, nullptr, dwT, nullptr, out, out, nullptr, rows, DD, DFFF);
}